// Round 6
// baseline (514.231 us; speedup 1.0000x reference)
//
#include <hip/hip_runtime.h>

// ---------------------------------------------------------------------------
// StructuralCausalModel: 3 layers x 32 vars sequential scan, BATCH=512.
// R13 (resubmit after infra failure): R12 (paW-transformed domain, 3
// barriers/step) +
//  (a) cross-step weight prefetch: W1/W2/W3P fragment sets double-buffered in
//      registers; step s issues step s+1's 20 b128 loads at its top, consumed
//      one full step later (~thousands of cycles of cover vs ~0 in R12).
//      Ping/pong via 2x-unrolled loop with named sets (no dynamic indexing).
//  (b) prep consolidation: prep_lin folded into prep_all; W3P compute blocks
//      write the swizzled bf16 fragment layout directly (each block's 8-row
//      m-octet is exactly one k-octet of the B-frag) -> no tmpf round-trip,
//      one fewer kernel launch.
// ---------------------------------------------------------------------------

typedef __bf16 bf16x8 __attribute__((ext_vector_type(8)));
typedef float  f32x4  __attribute__((ext_vector_type(4)));

#define N_VARS 32
#define BTILE 4
#define NBLK 128

// ---- ws byte offsets ----
#define WS_ADJB   0            // ushort[32*64]  (4 KB)
#define WS_B3P    4096         // float [32*256] (32 KB)
#define WS_EMBP   36864        // float [32*256] (32 KB)
#define WS_WSB    69632        // bf16 weight-fragment base
// element offsets within wsb (ushort elements)
#define ELOFF_PA  0
#define ELOFF_W1  65536
#define ELOFF_W2  1114112
#define ELOFF_W3  1638400
#define ELOFF_W3P 2686976
// wsb total el = 3735552 -> 7471104 B; ends at 69632+7471104 = 7540736
#define WS_NE2    7540736      // ushort[512*32*256] = 8 MB
// total ws = 15929344 B (~15.9 MB)

// LDS row strides (ushorts).
#define XSTR 272
#define HSTR 144
#define VSTR 40    // valsP col stride (80 B): b128 frag reads 16B-aligned

__device__ __forceinline__ unsigned short f2b(float f) {
    unsigned u = __float_as_uint(f);
    u += 0x7FFFu + ((u >> 16) & 1u);
    return (unsigned short)(u >> 16);
}

__device__ __forceinline__ float b2f(unsigned short u) {
    return __uint_as_float(((unsigned)u) << 16);
}

// lgkm-only barrier: LDS ordering enforced, global loads stay in flight.
__device__ __forceinline__ void bar_lds() {
    asm volatile("s_waitcnt lgkmcnt(0)\n\ts_barrier" ::: "memory");
}

// erf via Abramowitz-Stegun 7.1.25, 3 terms (|err| <= 2.5e-5)
__device__ __forceinline__ float gelu_e(float x) {
    float z  = x * 0.7071067811865476f;
    float az = fabsf(z);
    float t  = __builtin_amdgcn_rcpf(1.0f + 0.47047f * az);
    float p  = t * (0.3480242f + t * (-0.0958798f + t * 0.7478556f));
    float e  = 1.0f - p * __expf(-z * z);
    float er = (z < 0.0f) ? -e : e;
    return 0.5f * x * (1.0f + er);
}

// Extract element q (q = lane>>4, runtime) via compile-time-indexed selects.
__device__ __forceinline__ float pickq(f32x4 v, int q) {
    float lo = (q & 1) ? v[1] : v[0];
    float hi = (q & 1) ? v[3] : v[2];
    return (q & 2) ? hi : lo;
}
__device__ __forceinline__ float pick4(float x0, float x1, float x2, float x3, int q) {
    float lo = (q & 1) ? x1 : x0;
    float hi = (q & 1) ? x3 : x2;
    return (q & 2) ? hi : lo;
}

#define MFMA16(a, b, c) __builtin_amdgcn_mfma_f32_16x16x32_bf16(a, b, c, 0, 0, 0)

// ---------------------------------------------------------------------------
// prep_all (2121 blocks x 256):
//  [0,520):     weight swizzle via LDS tile (PA, W1, W2, W3)
//  520:         adjacency (bf16 hi/lo)
//  [521,1545):  noise encoder NE -> outp
//  [1545,2057): W3P = W3@paW compute (f32) + DIRECT swizzled bf16 write
//  [2057,2089): b3P = b3@paW
//  [2089,2121): embP = emb@paW + pab
// B-frag (16x16x32): lane l, elem j -> k = ks*32+(l>>4)*8+j, n = nt*16+(l&15)
// ---------------------------------------------------------------------------
__global__ void prep_all(const float* __restrict__ paW, const float* __restrict__ mW1,
                         const float* __restrict__ mW2, const float* __restrict__ mW3,
                         const float* __restrict__ edge, unsigned short* __restrict__ wsb,
                         unsigned short* __restrict__ adjb,
                         const float* __restrict__ noise, const float* __restrict__ neW,
                         const float* __restrict__ neb, float* __restrict__ outp,
                         const float* __restrict__ mb3, const float* __restrict__ emb,
                         const float* __restrict__ pab,
                         float* __restrict__ b3P, float* __restrict__ embP) {
    __shared__ unsigned short tile[32 * 256];
    const int c = blockIdx.x, tid = threadIdx.x;
    if (c < 520) {
        const float* src; unsigned short* dst; int N, KS, ks;
        if (c < 8)        { src = paW;                     dst = wsb + ELOFF_PA;             N = 256; KS = 8; ks = c; }
        else if (c < 264) { int v = (c - 8) >> 3;   ks = (c - 8) & 7;
                            src = mW1 + v * 32768;         dst = wsb + ELOFF_W1 + v * 32768; N = 128; KS = 8; }
        else if (c < 392) { int v = (c - 264) >> 2; ks = (c - 264) & 3;
                            src = mW2 + v * 16384;         dst = wsb + ELOFF_W2 + v * 16384; N = 128; KS = 4; }
        else              { int v = (c - 392) >> 2; ks = (c - 392) & 3;
                            src = mW3 + v * 32768;         dst = wsb + ELOFF_W3 + v * 32768; N = 256; KS = 4; }
        const int kb = ks * 32, nsh = (N == 256) ? 8 : 7;
        for (int t = tid; t < 32 * N; t += 256) {
            int r = t >> nsh, col = t & (N - 1);
            tile[r * N + col] = f2b(src[(kb + r) * N + col]);   // coalesced in col
        }
        __syncthreads();
        const int nout = (N >> 4) * 64;
        for (int o = tid; o < nout; o += 256) {
            int nt = o >> 6, lane = o & 63;
            int n = nt * 16 + (lane & 15), k0 = (lane >> 4) << 3;
            unsigned e[8];
            #pragma unroll
            for (int j = 0; j < 8; j++) e[j] = tile[(k0 + j) * N + n];
            uint4 pk;
            pk.x = e[0] | (e[1] << 16); pk.y = e[2] | (e[3] << 16);
            pk.z = e[4] | (e[5] << 16); pk.w = e[6] | (e[7] << 16);
            *(uint4*)(dst + ((nt * KS + ks) * 64 + lane) * 8) = pk;   // coalesced
        }
    } else if (c == 520) {
        for (int t = tid; t < 1024; t += 256) {
            int v = t >> 5, ci = t & 31;
            float x = edge[t];
            float m = (v == ci) ? 0.0f : x;   // diag logit masked -> adj diag = 0.5
            float a = __builtin_amdgcn_rcpf(1.0f + __expf(-2.0f * m));
            unsigned short hi = f2b(a);
            float rem = a - b2f(hi);
            adjb[ci * 64 + v]      = hi;        // row ci: parents-of-ci weights
            adjb[ci * 64 + 32 + v] = f2b(rem);  // low part (an ~ 16-bit mantissa)
        }
    } else if (c < 1545) {
        int sb = c - 521;                     // 1024 sub-blocks: 32 vars x 32 groups
        int i = sb >> 5, g = sb & 31, d = tid;
        float w[64];
        #pragma unroll
        for (int k = 0; k < 64; k++) w[k] = neW[(i * 64 + k) * 256 + d];
        float bias = neb[i * 256 + d];
        for (int bb = 0; bb < 16; bb++) {
            int b = g * 16 + bb;
            const float* nr = noise + (b * 32 + i) * 64;
            float a0 = bias, a1 = 0.f, a2 = 0.f, a3 = 0.f;
            #pragma unroll
            for (int k = 0; k < 16; k++) {      // 4 independent fma chains
                a0 += nr[4 * k + 0] * w[4 * k + 0];
                a1 += nr[4 * k + 1] * w[4 * k + 1];
                a2 += nr[4 * k + 2] * w[4 * k + 2];
                a3 += nr[4 * k + 3] * w[4 * k + 3];
            }
            outp[(b * 32 + i) * 256 + d] = gelu_e((a0 + a1) + (a2 + a3));
        }
    } else if (c < 2057) {
        // W3P[v][m][d] = sum_n W3[v][m][n]*paW[n][d]; one m-octet per block,
        // written DIRECTLY in swizzled B-frag layout (k-octet = m-octet).
        const int idx = c - 1545;
        const int v = idx >> 4, mg = (idx & 15) * 8;
        const int d = tid;
        const float* w3r = mW3 + (size_t)(v * 128 + mg) * 256;
        float acc[8];
        #pragma unroll
        for (int r = 0; r < 8; r++) acc[r] = 0.f;
        for (int n = 0; n < 256; n++) {
            float pa = paW[n * 256 + d];          // coalesced; w3r wave-uniform
            #pragma unroll
            for (int r = 0; r < 8; r++) acc[r] += w3r[r * 256 + n] * pa;
        }
        const int ks = mg >> 5, lg = (mg >> 3) & 3;
        const int nt = d >> 4, lane = lg * 16 + (d & 15);
        uint4 pk;
        pk.x = (unsigned)f2b(acc[0]) | ((unsigned)f2b(acc[1]) << 16);
        pk.y = (unsigned)f2b(acc[2]) | ((unsigned)f2b(acc[3]) << 16);
        pk.z = (unsigned)f2b(acc[4]) | ((unsigned)f2b(acc[5]) << 16);
        pk.w = (unsigned)f2b(acc[6]) | ((unsigned)f2b(acc[7]) << 16);
        *(uint4*)(wsb + ELOFF_W3P + v * 32768 + ((nt * 4 + ks) * 64 + lane) * 8) = pk;
    } else if (c < 2089) {
        const int v = c - 2057;
        float a = 0.f;
        for (int n = 0; n < 256; n++) a += mb3[v * 256 + n] * paW[n * 256 + tid];
        b3P[v * 256 + tid] = a;
    } else {
        const int v = c - 2089;
        float a = pab[tid];
        for (int n = 0; n < 256; n++) a += emb[v * 256 + n] * paW[n * 256 + tid];
        embP[v * 256 + tid] = a;
    }
}

// ---------------------------------------------------------------------------
// prep_ne2 (256 blocks x 256): NE2 = NE @ paW via MFMA, using the PA frags
// already swizzled into ws. Rows = 16384 (b*32+i); 1024 row-tiles of 16.
// ---------------------------------------------------------------------------
__global__ void prep_ne2(const float* __restrict__ nep, const __bf16* __restrict__ wsbf,
                         unsigned short* __restrict__ ne2) {
    const int tid = threadIdx.x;
    const int wid = tid >> 6, lane = tid & 63, l15 = lane & 15, q = lane >> 4;
    const int gt = blockIdx.x * 4 + wid;          // [0,1024)
    const int rowbase = gt * 16;
    bf16x8 afr[8];
    #pragma unroll
    for (int ks = 0; ks < 8; ks++) {
        const float* s = nep + (size_t)(rowbase + l15) * 256 + ks * 32 + q * 8;
        float4 x0 = *(const float4*)s;
        float4 x1 = *(const float4*)(s + 4);
        uint4 pk;
        pk.x = (unsigned)f2b(x0.x) | ((unsigned)f2b(x0.y) << 16);
        pk.y = (unsigned)f2b(x0.z) | ((unsigned)f2b(x0.w) << 16);
        pk.z = (unsigned)f2b(x1.x) | ((unsigned)f2b(x1.y) << 16);
        pk.w = (unsigned)f2b(x1.z) | ((unsigned)f2b(x1.w) << 16);
        afr[ks] = __builtin_bit_cast(bf16x8, pk);
    }
    #pragma unroll 4
    for (int nt = 0; nt < 16; nt++) {
        f32x4 e4 = {0, 0, 0, 0}, o4 = {0, 0, 0, 0};
        #pragma unroll
        for (int ks = 0; ks < 8; ks += 2) {
            bf16x8 b0 = *(const bf16x8*)(wsbf + ELOFF_PA + ((nt * 8 + ks) * 64 + lane) * 8);
            bf16x8 b1 = *(const bf16x8*)(wsbf + ELOFF_PA + ((nt * 8 + ks + 1) * 64 + lane) * 8);
            e4 = MFMA16(afr[ks], b0, e4);
            o4 = MFMA16(afr[ks + 1], b1, o4);
        }
        f32x4 a = e4 + o4;
        #pragma unroll
        for (int r = 0; r < 4; r++)
            ne2[(size_t)(rowbase + 4 * q + r) * 256 + nt * 16 + l15] = f2b(a[r]);
    }
}

// ---------------------------------------------------------------------------
// Main: 128 blocks x 512 threads. 3 barriers/step. Weight fragment sets
// double-buffered in registers; step s prefetches step s+1's set.
// B: W1 GEMM -> Hs1.  C: W2 GEMM -> Hs2; pcP GEMM; snap old.
// D: W3P GEMM + b3P + NE2 -> valsP[i]; lane-local fixup + gelu -> X2;
//    last layer only: raw W3 GEMM + b3 + NE -> outp.
// ---------------------------------------------------------------------------
__global__ __launch_bounds__(512) void
scm_main(const float* __restrict__ embP, const float* __restrict__ b3Pp,
         const float* __restrict__ mb1, const float* __restrict__ mb2,
         const float* __restrict__ mb3, const unsigned short* __restrict__ adjb,
         const __bf16* __restrict__ wsbf, const unsigned short* __restrict__ ne2,
         float* __restrict__ outp) {
    __shared__ unsigned short valsP[1024 * VSTR];  // [col=b*256+d][var] 80 KB
    __shared__ unsigned short X2[4 * XSTR];
    __shared__ unsigned short Hs1[4 * HSTR];
    __shared__ unsigned short Hs2[4 * HSTR];

    const int tid = threadIdx.x, blk = blockIdx.x;

    {   // zero valsP (1024*40 ushorts = 5120 uint4)
        uint4 z; z.x = z.y = z.z = z.w = 0;
        for (int k = tid; k < 5120; k += 512) ((uint4*)valsP)[k] = z;
    }

    const int wid = tid >> 6, lane = tid & 63, l15 = lane & 15, q = lane >> 4;
    const int l3 = l15 & 3;                 // A-frag row (BTILE=4; rows alias)
    const int nW = wid * 16 + l15;
    const int n0 = nW, n1 = nW + 128;

    // seed X2 for step 0: valsP = 0 -> pcP = 0 -> X2 = gelu(embP'_0)
    X2[q * XSTR + n0] = f2b(gelu_e(embP[n0]));
    X2[q * XSTR + n1] = f2b(gelu_e(embP[n1]));
    bar_lds();

    // ---- double-buffered weight fragment sets ----
    bf16x8 wa1[8], wa2[4], waP0[4], waP1[4];
    bf16x8 wb1[8], wb2[4], wbP0[4], wbP1[4];

    auto loadw = [&](int i, bf16x8 (&w1)[8], bf16x8 (&w2)[4],
                     bf16x8 (&wP0)[4], bf16x8 (&wP1)[4]) {
        #pragma unroll
        for (int ks = 0; ks < 8; ks++)
            w1[ks] = *(const bf16x8*)(wsbf + ELOFF_W1 + (size_t)i * 32768 +
                                      ((wid * 8 + ks) * 64 + lane) * 8);
        #pragma unroll
        for (int ks = 0; ks < 4; ks++) {
            w2[ks]  = *(const bf16x8*)(wsbf + ELOFF_W2 + (size_t)i * 16384 +
                                       ((wid * 4 + ks) * 64 + lane) * 8);
            wP0[ks] = *(const bf16x8*)(wsbf + ELOFF_W3P + (size_t)i * 32768 +
                                       ((wid * 4 + ks) * 64 + lane) * 8);
            wP1[ks] = *(const bf16x8*)(wsbf + ELOFF_W3P + (size_t)i * 32768 +
                                       (((wid + 8) * 4 + ks) * 64 + lane) * 8);
        }
    };

    auto step = [&](int s, bf16x8 (&w1f)[8], bf16x8 (&w2f)[4],
                    bf16x8 (&wPf0)[4], bf16x8 (&wPf1)[4],
                    bf16x8 (&x1)[8], bf16x8 (&x2)[4],
                    bf16x8 (&xP0)[4], bf16x8 (&xP1)[4]) {
        const int i = s & 31, ni = (s + 1) & 31;
        const bool last = s >= 64;

        // ---- prefetch NEXT step's weight set (consumed one step later) ----
        loadw(ni, x1, x2, xP0, xP1);

        // ---- current-step scalars (covered by stages B/C before use) ----
        float bi1 = mb1[i * 128 + nW];
        float bi2 = mb2[i * 128 + nW];
        const size_t nrow = ((size_t)(blk * BTILE + q) * 32 + i) * 256;
        const float ne2_0 = b2f(ne2[nrow + n0]);
        const float ne2_1 = b2f(ne2[nrow + n1]);
        const float b3P0 = b3Pp[i * 256 + n0];
        const float b3P1 = b3Pp[i * 256 + n1];
        const float eP0 = embP[ni * 256 + n0];
        const float eP1 = embP[ni * 256 + n1];
        bf16x8 anh = *(const bf16x8*)(adjb + ni * 64 + q * 8);
        bf16x8 anl = *(const bf16x8*)(adjb + ni * 64 + 32 + q * 8);
        const float ani = b2f(adjb[ni * 64 + i]) + b2f(adjb[ni * 64 + 32 + i]);
        bf16x8 w3f0[4], w3f1[4];
        float b3a = 0.f, b3b = 0.f, neq0 = 0.f, neq1 = 0.f;
        if (last) {
            #pragma unroll
            for (int ks = 0; ks < 4; ks++) {
                w3f0[ks] = *(const bf16x8*)(wsbf + ELOFF_W3 + (size_t)i * 32768 +
                                            ((wid * 4 + ks) * 64 + lane) * 8);
                w3f1[ks] = *(const bf16x8*)(wsbf + ELOFF_W3 + (size_t)i * 32768 +
                                            (((wid + 8) * 4 + ks) * 64 + lane) * 8);
            }
            b3a = mb3[i * 256 + n0];
            b3b = mb3[i * 256 + n1];
            neq0 = outp[nrow + n0];
            neq1 = outp[nrow + n1];
        }

        // ==== B: W1 GEMM on X2 -> Hs1 ====
        {
            f32x4 aa = {0, 0, 0, 0}, ab = {0, 0, 0, 0};
            f32x4 ac = {0, 0, 0, 0}, ad = {0, 0, 0, 0};
            #pragma unroll
            for (int ks = 0; ks < 8; ks += 4) {
                bf16x8 af0 = *(const bf16x8*)(X2 + l3 * XSTR + ks * 32 + q * 8);
                bf16x8 af1 = *(const bf16x8*)(X2 + l3 * XSTR + (ks + 1) * 32 + q * 8);
                bf16x8 af2 = *(const bf16x8*)(X2 + l3 * XSTR + (ks + 2) * 32 + q * 8);
                bf16x8 af3 = *(const bf16x8*)(X2 + l3 * XSTR + (ks + 3) * 32 + q * 8);
                aa = MFMA16(af0, w1f[ks], aa);
                ab = MFMA16(af1, w1f[ks + 1], ab);
                ac = MFMA16(af2, w1f[ks + 2], ac);
                ad = MFMA16(af3, w1f[ks + 3], ad);
            }
            float sb = (pickq(aa, q) + pickq(ab, q)) +
                       (pickq(ac, q) + pickq(ad, q)) + bi1;
            Hs1[q * HSTR + nW] = f2b(gelu_e(sb));
        }
        bar_lds();

        // ==== C: W2 GEMM; pcP GEMM (pre-update valsP, hi/lo an); snap old ====
        f32x4 P0[4], P1[4];
        float oP0, oP1;
        {
            f32x4 ca = {0, 0, 0, 0}, cb = {0, 0, 0, 0};
            #pragma unroll
            for (int ks = 0; ks < 4; ks += 2) {
                bf16x8 af0 = *(const bf16x8*)(Hs1 + l3 * HSTR + ks * 32 + q * 8);
                bf16x8 af1 = *(const bf16x8*)(Hs1 + l3 * HSTR + (ks + 1) * 32 + q * 8);
                ca = MFMA16(af0, w2f[ks], ca);
                cb = MFMA16(af1, w2f[ks + 1], cb);
            }
            // pcP: one K=32 tile per (b=t, col set). B-frag = 8 contiguous vars.
            #pragma unroll
            for (int t = 0; t < 4; t++) {
                bf16x8 vf0 = *(const bf16x8*)(valsP + (t * 256 + n0) * VSTR + q * 8);
                bf16x8 vf1 = *(const bf16x8*)(valsP + (t * 256 + n1) * VSTR + q * 8);
                f32x4 z = {0, 0, 0, 0};
                P0[t] = MFMA16(anl, vf0, MFMA16(anh, vf0, z));
                P1[t] = MFMA16(anl, vf1, MFMA16(anh, vf1, z));
            }
            oP0 = b2f(valsP[(q * 256 + n0) * VSTR + i]);
            oP1 = b2f(valsP[(q * 256 + n1) * VSTR + i]);
            float scv = pickq(ca, q) + pickq(cb, q) + bi2;
            Hs2[q * HSTR + nW] = f2b(gelu_e(scv));
        }
        bar_lds();

        // ==== D: W3P GEMM -> valsP[i]; fixup + gelu -> X2; (last: W3 -> outp) ====
        {
            f32x4 c0a = {0, 0, 0, 0}, c0b = {0, 0, 0, 0};
            f32x4 c1a = {0, 0, 0, 0}, c1b = {0, 0, 0, 0};
            #pragma unroll
            for (int ks = 0; ks < 4; ks += 2) {
                bf16x8 af0 = *(const bf16x8*)(Hs2 + l3 * HSTR + ks * 32 + q * 8);
                bf16x8 af1 = *(const bf16x8*)(Hs2 + l3 * HSTR + (ks + 1) * 32 + q * 8);
                c0a = MFMA16(af0, wPf0[ks], c0a);
                c1a = MFMA16(af0, wPf1[ks], c1a);
                c0b = MFMA16(af1, wPf0[ks + 1], c0b);
                c1b = MFMA16(af1, wPf1[ks + 1], c1b);
            }
            float nP0 = pickq(c0a, q) + pickq(c0b, q) + b3P0 + ne2_0;
            float nP1 = pickq(c1a, q) + pickq(c1b, q) + b3P1 + ne2_1;
            unsigned short ur0 = f2b(nP0), ur1 = f2b(nP1);
            valsP[(q * 256 + n0) * VSTR + i] = ur0;
            valsP[(q * 256 + n1) * VSTR + i] = ur1;
            // lane-local fixup in transformed domain -> X2 for step ni
            float pc0 = pick4(P0[0][0], P0[1][0], P0[2][0], P0[3][0], q);
            float pc1 = pick4(P1[0][0], P1[1][0], P1[2][0], P1[3][0], q);
            float x0 = pc0 + ani * (b2f(ur0) - oP0) + eP0;
            float x1 = pc1 + ani * (b2f(ur1) - oP1) + eP1;
            X2[q * XSTR + n0] = f2b(gelu_e(x0));
            X2[q * XSTR + n1] = f2b(gelu_e(x1));
            if (last) {
                f32x4 d0a = {0, 0, 0, 0}, d0b = {0, 0, 0, 0};
                f32x4 d1a = {0, 0, 0, 0}, d1b = {0, 0, 0, 0};
                #pragma unroll
                for (int ks = 0; ks < 4; ks += 2) {
                    bf16x8 af0 = *(const bf16x8*)(Hs2 + l3 * HSTR + ks * 32 + q * 8);
                    bf16x8 af1 = *(const bf16x8*)(Hs2 + l3 * HSTR + (ks + 1) * 32 + q * 8);
                    d0a = MFMA16(af0, w3f0[ks], d0a);
                    d1a = MFMA16(af0, w3f1[ks], d1a);
                    d0b = MFMA16(af1, w3f0[ks + 1], d0b);
                    d1b = MFMA16(af1, w3f1[ks + 1], d1b);
                }
                outp[nrow + n0] = pickq(d0a, q) + pickq(d0b, q) + b3a + neq0;
                outp[nrow + n1] = pickq(d1a, q) + pickq(d1b, q) + b3b + neq1;
            }
        }
        bar_lds();
    };

    loadw(0, wa1, wa2, waP0, waP1);
    for (int ss = 0; ss < 48; ss++) {
        step(2 * ss,     wa1, wa2, waP0, waP1, wb1, wb2, wbP0, wbP1);
        step(2 * ss + 1, wb1, wb2, wbP0, wbP1, wa1, wa2, waP0, waP1);
    }
}

extern "C" void kernel_launch(void* const* d_in, const int* in_sizes, int n_in,
                              void* d_out, int out_size, void* d_ws, size_t ws_size,
                              hipStream_t stream) {
    (void)in_sizes; (void)n_in; (void)out_size; (void)ws_size;
    const float* noise = (const float*)d_in[0];
    const float* edge  = (const float*)d_in[1];
    const float* emb   = (const float*)d_in[2];
    const float* paW   = (const float*)d_in[3];
    const float* pab   = (const float*)d_in[4];
    const float* mW1   = (const float*)d_in[5];
    const float* mb1   = (const float*)d_in[6];
    const float* mW2   = (const float*)d_in[7];
    const float* mb2   = (const float*)d_in[8];
    const float* mW3   = (const float*)d_in[9];
    const float* mb3   = (const float*)d_in[10];
    const float* neW   = (const float*)d_in[11];
    const float* neb   = (const float*)d_in[12];
    float* outp = (float*)d_out;

    unsigned short* adjb = (unsigned short*)((char*)d_ws + WS_ADJB);
    float* b3P  = (float*)((char*)d_ws + WS_B3P);
    float* embP = (float*)((char*)d_ws + WS_EMBP);
    unsigned short* wsb  = (unsigned short*)((char*)d_ws + WS_WSB);
    unsigned short* ne2u = (unsigned short*)((char*)d_ws + WS_NE2);

    prep_all<<<2121, 256, 0, stream>>>(paW, mW1, mW2, mW3, edge, wsb, adjb,
                                       noise, neW, neb, outp, mb3, emb, pab,
                                       b3P, embP);
    prep_ne2<<<256, 256, 0, stream>>>(outp, (const __bf16*)wsb, ne2u);
    scm_main<<<NBLK, 512, 0, stream>>>(embP, b3P, mb1, mb2, mb3, adjb,
                                       (const __bf16*)wsb, ne2u, outp);
}

// Round 7
// 396.662 us; speedup vs baseline: 1.2964x; 1.2964x over previous
//
#include <hip/hip_runtime.h>

// ---------------------------------------------------------------------------
// StructuralCausalModel: 3 layers x 32 vars sequential scan, BATCH=512.
// R14: R12 structure (3 barriers/step, transform domain) +
//  (a) __launch_bounds__(512,2): 256-VGPR budget (R13 spilled at default 128)
//  (b) w1f ONLY double-buffered across steps (zero-cover load); W2/W3P stay
//      top-of-step (1-2 stages of cover). +32 VGPR, not +80.
//  (c) pcP C-regs reduced inline (only [0] of tile q used) -> -24 live VGPR.
//  (d) NE2 computed in per-block MFMA prologue into LDS ne2S (64 KB);
//      prep_ne2 kernel + 8MB NE2 traffic deleted; in-loop ne2 = ds_read.
//  (e) last-layer raw-W3 path off the serial chain: stage C stores h2 (bf16)
//      to h2buf; post_out kernel computes outp = h2@W3 + b3 + ne.
// LDS 151.9 KB (1 block/CU). Kernels: prep_all -> scm_main -> post_out.
// ---------------------------------------------------------------------------

typedef __bf16 bf16x8 __attribute__((ext_vector_type(8)));
typedef float  f32x4  __attribute__((ext_vector_type(4)));

#define N_VARS 32
#define BTILE 4
#define NBLK 128

// ---- ws byte offsets ----
#define WS_ADJB   0            // ushort[32*64]  (4 KB)
#define WS_B3P    4096         // float [32*256] (32 KB)
#define WS_EMBP   36864        // float [32*256] (32 KB)
#define WS_WSB    69632        // bf16 weight-fragment base
// element offsets within wsb (ushort elements)
#define ELOFF_PA  0
#define ELOFF_W1  65536
#define ELOFF_W2  1114112
#define ELOFF_W3  1638400
#define ELOFF_W3P 2686976
// wsb total el = 3735552 -> 7471104 B; ends at 69632+7471104 = 7540736
#define WS_H2B    7540736      // ushort[32*512*128] = 4 MB (h2 of last layer)
// total ws < 16 MB

// LDS row strides (ushorts).
#define XSTR 272
#define HSTR 144
#define VSTR 40    // valsP col stride (80 B): b128 frag reads 16B-aligned

__device__ __forceinline__ unsigned short f2b(float f) {
    unsigned u = __float_as_uint(f);
    u += 0x7FFFu + ((u >> 16) & 1u);
    return (unsigned short)(u >> 16);
}

__device__ __forceinline__ float b2f(unsigned short u) {
    return __uint_as_float(((unsigned)u) << 16);
}

// lgkm-only barrier: LDS ordering enforced, global loads stay in flight.
__device__ __forceinline__ void bar_lds() {
    asm volatile("s_waitcnt lgkmcnt(0)\n\ts_barrier" ::: "memory");
}

// erf via Abramowitz-Stegun 7.1.25, 3 terms (|err| <= 2.5e-5)
__device__ __forceinline__ float gelu_e(float x) {
    float z  = x * 0.7071067811865476f;
    float az = fabsf(z);
    float t  = __builtin_amdgcn_rcpf(1.0f + 0.47047f * az);
    float p  = t * (0.3480242f + t * (-0.0958798f + t * 0.7478556f));
    float e  = 1.0f - p * __expf(-z * z);
    float er = (z < 0.0f) ? -e : e;
    return 0.5f * x * (1.0f + er);
}

// Extract element q (q = lane>>4, runtime) via compile-time-indexed selects.
__device__ __forceinline__ float pickq(f32x4 v, int q) {
    float lo = (q & 1) ? v[1] : v[0];
    float hi = (q & 1) ? v[3] : v[2];
    return (q & 2) ? hi : lo;
}

#define MFMA16(a, b, c) __builtin_amdgcn_mfma_f32_16x16x32_bf16(a, b, c, 0, 0, 0)

// ---------------------------------------------------------------------------
// prep_all (2121 blocks x 256):
//  [0,520):     weight swizzle via LDS tile (PA, W1, W2, W3)
//  520:         adjacency (bf16 hi/lo)
//  [521,1545):  noise encoder NE -> outp
//  [1545,2057): W3P = W3@paW compute (f32) + DIRECT swizzled bf16 write
//  [2057,2089): b3P = b3@paW
//  [2089,2121): embP = emb@paW + pab
// B-frag (16x16x32): lane l, elem j -> k = ks*32+(l>>4)*8+j, n = nt*16+(l&15)
// ---------------------------------------------------------------------------
__global__ void prep_all(const float* __restrict__ paW, const float* __restrict__ mW1,
                         const float* __restrict__ mW2, const float* __restrict__ mW3,
                         const float* __restrict__ edge, unsigned short* __restrict__ wsb,
                         unsigned short* __restrict__ adjb,
                         const float* __restrict__ noise, const float* __restrict__ neW,
                         const float* __restrict__ neb, float* __restrict__ outp,
                         const float* __restrict__ mb3, const float* __restrict__ emb,
                         const float* __restrict__ pab,
                         float* __restrict__ b3P, float* __restrict__ embP) {
    __shared__ unsigned short tile[32 * 256];
    const int c = blockIdx.x, tid = threadIdx.x;
    if (c < 520) {
        const float* src; unsigned short* dst; int N, KS, ks;
        if (c < 8)        { src = paW;                     dst = wsb + ELOFF_PA;             N = 256; KS = 8; ks = c; }
        else if (c < 264) { int v = (c - 8) >> 3;   ks = (c - 8) & 7;
                            src = mW1 + v * 32768;         dst = wsb + ELOFF_W1 + v * 32768; N = 128; KS = 8; }
        else if (c < 392) { int v = (c - 264) >> 2; ks = (c - 264) & 3;
                            src = mW2 + v * 16384;         dst = wsb + ELOFF_W2 + v * 16384; N = 128; KS = 4; }
        else              { int v = (c - 392) >> 2; ks = (c - 392) & 3;
                            src = mW3 + v * 32768;         dst = wsb + ELOFF_W3 + v * 32768; N = 256; KS = 4; }
        const int kb = ks * 32, nsh = (N == 256) ? 8 : 7;
        for (int t = tid; t < 32 * N; t += 256) {
            int r = t >> nsh, col = t & (N - 1);
            tile[r * N + col] = f2b(src[(kb + r) * N + col]);   // coalesced in col
        }
        __syncthreads();
        const int nout = (N >> 4) * 64;
        for (int o = tid; o < nout; o += 256) {
            int nt = o >> 6, lane = o & 63;
            int n = nt * 16 + (lane & 15), k0 = (lane >> 4) << 3;
            unsigned e[8];
            #pragma unroll
            for (int j = 0; j < 8; j++) e[j] = tile[(k0 + j) * N + n];
            uint4 pk;
            pk.x = e[0] | (e[1] << 16); pk.y = e[2] | (e[3] << 16);
            pk.z = e[4] | (e[5] << 16); pk.w = e[6] | (e[7] << 16);
            *(uint4*)(dst + ((nt * KS + ks) * 64 + lane) * 8) = pk;   // coalesced
        }
    } else if (c == 520) {
        for (int t = tid; t < 1024; t += 256) {
            int v = t >> 5, ci = t & 31;
            float x = edge[t];
            float m = (v == ci) ? 0.0f : x;   // diag logit masked -> adj diag = 0.5
            float a = __builtin_amdgcn_rcpf(1.0f + __expf(-2.0f * m));
            unsigned short hi = f2b(a);
            float rem = a - b2f(hi);
            adjb[ci * 64 + v]      = hi;        // row ci: parents-of-ci weights
            adjb[ci * 64 + 32 + v] = f2b(rem);  // low part (an ~ 16-bit mantissa)
        }
    } else if (c < 1545) {
        int sb = c - 521;                     // 1024 sub-blocks: 32 vars x 32 groups
        int i = sb >> 5, g = sb & 31, d = tid;
        float w[64];
        #pragma unroll
        for (int k = 0; k < 64; k++) w[k] = neW[(i * 64 + k) * 256 + d];
        float bias = neb[i * 256 + d];
        for (int bb = 0; bb < 16; bb++) {
            int b = g * 16 + bb;
            const float* nr = noise + (b * 32 + i) * 64;
            float a0 = bias, a1 = 0.f, a2 = 0.f, a3 = 0.f;
            #pragma unroll
            for (int k = 0; k < 16; k++) {      // 4 independent fma chains
                a0 += nr[4 * k + 0] * w[4 * k + 0];
                a1 += nr[4 * k + 1] * w[4 * k + 1];
                a2 += nr[4 * k + 2] * w[4 * k + 2];
                a3 += nr[4 * k + 3] * w[4 * k + 3];
            }
            outp[(b * 32 + i) * 256 + d] = gelu_e((a0 + a1) + (a2 + a3));
        }
    } else if (c < 2057) {
        // W3P[v][m][d] = sum_n W3[v][m][n]*paW[n][d]; one m-octet per block,
        // written DIRECTLY in swizzled B-frag layout (k-octet = m-octet).
        const int idx = c - 1545;
        const int v = idx >> 4, mg = (idx & 15) * 8;
        const int d = tid;
        const float* w3r = mW3 + (size_t)(v * 128 + mg) * 256;
        float acc[8];
        #pragma unroll
        for (int r = 0; r < 8; r++) acc[r] = 0.f;
        for (int n = 0; n < 256; n++) {
            float pa = paW[n * 256 + d];          // coalesced; w3r wave-uniform
            #pragma unroll
            for (int r = 0; r < 8; r++) acc[r] += w3r[r * 256 + n] * pa;
        }
        const int ks = mg >> 5, lg = (mg >> 3) & 3;
        const int nt = d >> 4, lane = lg * 16 + (d & 15);
        uint4 pk;
        pk.x = (unsigned)f2b(acc[0]) | ((unsigned)f2b(acc[1]) << 16);
        pk.y = (unsigned)f2b(acc[2]) | ((unsigned)f2b(acc[3]) << 16);
        pk.z = (unsigned)f2b(acc[4]) | ((unsigned)f2b(acc[5]) << 16);
        pk.w = (unsigned)f2b(acc[6]) | ((unsigned)f2b(acc[7]) << 16);
        *(uint4*)(wsb + ELOFF_W3P + v * 32768 + ((nt * 4 + ks) * 64 + lane) * 8) = pk;
    } else if (c < 2089) {
        const int v = c - 2057;
        float a = 0.f;
        for (int n = 0; n < 256; n++) a += mb3[v * 256 + n] * paW[n * 256 + tid];
        b3P[v * 256 + tid] = a;
    } else {
        const int v = c - 2089;
        float a = pab[tid];
        for (int n = 0; n < 256; n++) a += emb[v * 256 + n] * paW[n * 256 + tid];
        embP[v * 256 + tid] = a;
    }
}

// ---------------------------------------------------------------------------
// Main: 128 blocks x 512 threads, launch_bounds(512,2) -> 256 VGPR budget.
// Prologue: NE2 = NE@paW per block via MFMA into LDS ne2S (64 KB).
// Per step (3 barriers): B: W1(double-buffered) -> Hs1.
// C: W2 + pcP(inline-reduced) -> Hs2 (+h2buf store in last layer).
// D: W3P -> valsP[i]; lane-local fixup + gelu -> X2.
// ---------------------------------------------------------------------------
__global__ __launch_bounds__(512, 2) void
scm_main(const float* __restrict__ embP, const float* __restrict__ b3Pp,
         const float* __restrict__ mb1, const float* __restrict__ mb2,
         const unsigned short* __restrict__ adjb,
         const __bf16* __restrict__ wsbf, const float* __restrict__ outp,
         unsigned short* __restrict__ h2buf) {
    __shared__ unsigned short valsP[1024 * VSTR];   // 80 KB
    __shared__ unsigned short ne2S[4 * 32 * 256];   // 64 KB  [(b-row*32+i)*256+d]
    __shared__ unsigned short X2[4 * XSTR];
    __shared__ unsigned short Hs1[4 * HSTR];
    __shared__ unsigned short Hs2[4 * HSTR];

    const int tid = threadIdx.x, blk = blockIdx.x;

    {   // zero valsP (1024*40 ushorts = 5120 uint4)
        uint4 z; z.x = z.y = z.z = z.w = 0;
        for (int k = tid; k < 5120; k += 512) ((uint4*)valsP)[k] = z;
    }

    const int wid = tid >> 6, lane = tid & 63, l15 = lane & 15, q = lane >> 4;
    const int l3 = l15 & 3;                 // A-frag row (BTILE=4; rows alias)
    const int nW = wid * 16 + l15;
    const int n0 = nW, n1 = nW + 128;

    // ---- prologue: ne2S[(r*32+i)*256+d] = (NE @ paW)[blk*4+r, i, d] ----
    {
        const int R = wid * 16 + l15;               // row id: r=R>>5, i=R&31
        const float* src = outp + ((size_t)(blk * BTILE + (R >> 5)) * 32 + (R & 31)) * 256 + q * 8;
        bf16x8 afr[8];
        #pragma unroll
        for (int ks = 0; ks < 8; ks++) {
            float4 x0 = *(const float4*)(src + ks * 32);
            float4 x1 = *(const float4*)(src + ks * 32 + 4);
            uint4 pk;
            pk.x = (unsigned)f2b(x0.x) | ((unsigned)f2b(x0.y) << 16);
            pk.y = (unsigned)f2b(x0.z) | ((unsigned)f2b(x0.w) << 16);
            pk.z = (unsigned)f2b(x1.x) | ((unsigned)f2b(x1.y) << 16);
            pk.w = (unsigned)f2b(x1.z) | ((unsigned)f2b(x1.w) << 16);
            afr[ks] = __builtin_bit_cast(bf16x8, pk);
        }
        #pragma unroll 4
        for (int nt = 0; nt < 16; nt++) {
            f32x4 e4 = {0, 0, 0, 0}, o4 = {0, 0, 0, 0};
            #pragma unroll
            for (int ks = 0; ks < 8; ks += 2) {
                bf16x8 b0 = *(const bf16x8*)(wsbf + ELOFF_PA + ((nt * 8 + ks) * 64 + lane) * 8);
                bf16x8 b1 = *(const bf16x8*)(wsbf + ELOFF_PA + ((nt * 8 + ks + 1) * 64 + lane) * 8);
                e4 = MFMA16(afr[ks], b0, e4);
                o4 = MFMA16(afr[ks + 1], b1, o4);
            }
            f32x4 a = e4 + o4;
            #pragma unroll
            for (int rr = 0; rr < 4; rr++) {
                int R2 = wid * 16 + q * 4 + rr;     // (r2*32+i2) packed
                ne2S[R2 * 256 + nt * 16 + l15] = f2b(a[rr]);
            }
        }
    }

    // seed X2 for step 0: valsP = 0 -> pcP = 0 -> X2 = gelu(embP'_0)
    X2[q * XSTR + n0] = f2b(gelu_e(embP[n0]));
    X2[q * XSTR + n1] = f2b(gelu_e(embP[n1]));
    bar_lds();

    auto step = [&](int s, bf16x8 (&w1f)[8], bf16x8 (&w1n)[8]) {
        const int i = s & 31, ni = (s + 1) & 31;
        const bool last = s >= 64;

        // ---- prefetch NEXT step's W1 (consumed one full step later) ----
        #pragma unroll
        for (int ks = 0; ks < 8; ks++)
            w1n[ks] = *(const bf16x8*)(wsbf + ELOFF_W1 + (size_t)ni * 32768 +
                                       ((wid * 8 + ks) * 64 + lane) * 8);
        // ---- current-step W2/W3P (used in C/D: 1-2 stages of cover) ----
        bf16x8 w2f[4], wPf0[4], wPf1[4];
        #pragma unroll
        for (int ks = 0; ks < 4; ks++) {
            w2f[ks]  = *(const bf16x8*)(wsbf + ELOFF_W2 + (size_t)i * 16384 +
                                        ((wid * 4 + ks) * 64 + lane) * 8);
            wPf0[ks] = *(const bf16x8*)(wsbf + ELOFF_W3P + (size_t)i * 32768 +
                                        ((wid * 4 + ks) * 64 + lane) * 8);
            wPf1[ks] = *(const bf16x8*)(wsbf + ELOFF_W3P + (size_t)i * 32768 +
                                        (((wid + 8) * 4 + ks) * 64 + lane) * 8);
        }
        // ---- per-step scalars ----
        float bi1 = mb1[i * 128 + nW];
        float bi2 = mb2[i * 128 + nW];
        const float ne2_0 = b2f(ne2S[(q * 32 + i) * 256 + n0]);
        const float ne2_1 = b2f(ne2S[(q * 32 + i) * 256 + n1]);
        const float b3P0 = b3Pp[i * 256 + n0];
        const float b3P1 = b3Pp[i * 256 + n1];
        const float eP0 = embP[ni * 256 + n0];
        const float eP1 = embP[ni * 256 + n1];
        bf16x8 anh = *(const bf16x8*)(adjb + ni * 64 + q * 8);
        bf16x8 anl = *(const bf16x8*)(adjb + ni * 64 + 32 + q * 8);
        const float ani = b2f(adjb[ni * 64 + i]) + b2f(adjb[ni * 64 + 32 + i]);

        // ==== B: W1 GEMM on X2 -> Hs1 ====
        {
            f32x4 aa = {0, 0, 0, 0}, ab = {0, 0, 0, 0};
            f32x4 ac = {0, 0, 0, 0}, ad = {0, 0, 0, 0};
            #pragma unroll
            for (int ks = 0; ks < 8; ks += 4) {
                bf16x8 af0 = *(const bf16x8*)(X2 + l3 * XSTR + ks * 32 + q * 8);
                bf16x8 af1 = *(const bf16x8*)(X2 + l3 * XSTR + (ks + 1) * 32 + q * 8);
                bf16x8 af2 = *(const bf16x8*)(X2 + l3 * XSTR + (ks + 2) * 32 + q * 8);
                bf16x8 af3 = *(const bf16x8*)(X2 + l3 * XSTR + (ks + 3) * 32 + q * 8);
                aa = MFMA16(af0, w1f[ks], aa);
                ab = MFMA16(af1, w1f[ks + 1], ab);
                ac = MFMA16(af2, w1f[ks + 2], ac);
                ad = MFMA16(af3, w1f[ks + 3], ad);
            }
            float sb = (pickq(aa, q) + pickq(ab, q)) +
                       (pickq(ac, q) + pickq(ad, q)) + bi1;
            Hs1[q * HSTR + nW] = f2b(gelu_e(sb));
        }
        bar_lds();

        // ==== C: W2 GEMM; pcP GEMM (inline-reduced); snap old; h2 store ====
        float pc0 = 0.f, pc1 = 0.f, oP0, oP1;
        {
            f32x4 ca = {0, 0, 0, 0}, cb = {0, 0, 0, 0};
            #pragma unroll
            for (int ks = 0; ks < 4; ks += 2) {
                bf16x8 af0 = *(const bf16x8*)(Hs1 + l3 * HSTR + ks * 32 + q * 8);
                bf16x8 af1 = *(const bf16x8*)(Hs1 + l3 * HSTR + (ks + 1) * 32 + q * 8);
                ca = MFMA16(af0, w2f[ks], ca);
                cb = MFMA16(af1, w2f[ks + 1], cb);
            }
            // pcP: K=32 tile per b=t; all C rows identical (A rows = an);
            // lane keeps only its own tile's element [0].
            #pragma unroll
            for (int t = 0; t < 4; t++) {
                bf16x8 vf0 = *(const bf16x8*)(valsP + (t * 256 + n0) * VSTR + q * 8);
                bf16x8 vf1 = *(const bf16x8*)(valsP + (t * 256 + n1) * VSTR + q * 8);
                f32x4 z = {0, 0, 0, 0};
                f32x4 p0 = MFMA16(anl, vf0, MFMA16(anh, vf0, z));
                f32x4 p1 = MFMA16(anl, vf1, MFMA16(anh, vf1, z));
                pc0 = (q == t) ? p0[0] : pc0;
                pc1 = (q == t) ? p1[0] : pc1;
            }
            oP0 = b2f(valsP[(q * 256 + n0) * VSTR + i]);
            oP1 = b2f(valsP[(q * 256 + n1) * VSTR + i]);
            float scv = pickq(ca, q) + pickq(cb, q) + bi2;
            unsigned short hv = f2b(gelu_e(scv));
            Hs2[q * HSTR + nW] = hv;
            if (last)
                h2buf[((size_t)i * 512 + blk * BTILE + q) * 128 + nW] = hv;
        }
        bar_lds();

        // ==== D: W3P GEMM -> valsP[i]; lane-local fixup + gelu -> X2 ====
        {
            f32x4 c0a = {0, 0, 0, 0}, c0b = {0, 0, 0, 0};
            f32x4 c1a = {0, 0, 0, 0}, c1b = {0, 0, 0, 0};
            #pragma unroll
            for (int ks = 0; ks < 4; ks += 2) {
                bf16x8 af0 = *(const bf16x8*)(Hs2 + l3 * HSTR + ks * 32 + q * 8);
                bf16x8 af1 = *(const bf16x8*)(Hs2 + l3 * HSTR + (ks + 1) * 32 + q * 8);
                c0a = MFMA16(af0, wPf0[ks], c0a);
                c1a = MFMA16(af0, wPf1[ks], c1a);
                c0b = MFMA16(af1, wPf0[ks + 1], c0b);
                c1b = MFMA16(af1, wPf1[ks + 1], c1b);
            }
            float nP0 = pickq(c0a, q) + pickq(c0b, q) + b3P0 + ne2_0;
            float nP1 = pickq(c1a, q) + pickq(c1b, q) + b3P1 + ne2_1;
            unsigned short ur0 = f2b(nP0), ur1 = f2b(nP1);
            valsP[(q * 256 + n0) * VSTR + i] = ur0;
            valsP[(q * 256 + n1) * VSTR + i] = ur1;
            float x0 = pc0 + ani * (b2f(ur0) - oP0) + eP0;
            float x1 = pc1 + ani * (b2f(ur1) - oP1) + eP1;
            X2[q * XSTR + n0] = f2b(gelu_e(x0));
            X2[q * XSTR + n1] = f2b(gelu_e(x1));
        }
        bar_lds();
    };

    bf16x8 w1a[8], w1b[8];
    #pragma unroll
    for (int ks = 0; ks < 8; ks++)      // W1 for step 0
        w1a[ks] = *(const bf16x8*)(wsbf + ELOFF_W1 +
                                   ((wid * 8 + ks) * 64 + lane) * 8);
    for (int ss = 0; ss < 48; ss++) {
        step(2 * ss,     w1a, w1b);
        step(2 * ss + 1, w1b, w1a);
    }
}

// ---------------------------------------------------------------------------
// post_out (256 blocks x 256): outp = h2 @ W3 + b3 + ne  (ne already in outp).
// Wave gid in [0,1024): i = gid>>5, bt = gid&31 -> rows b = bt*16..+15.
// ---------------------------------------------------------------------------
__global__ __launch_bounds__(256) void
post_out(const unsigned short* __restrict__ h2buf, const __bf16* __restrict__ wsbf,
         const float* __restrict__ mb3, float* __restrict__ outp) {
    const int tid = threadIdx.x;
    const int wid = tid >> 6, lane = tid & 63, l15 = lane & 15, q = lane >> 4;
    const int gid = blockIdx.x * 4 + wid;
    const int i = gid >> 5, bt = gid & 31;
    bf16x8 af[4];
    #pragma unroll
    for (int ks = 0; ks < 4; ks++)
        af[ks] = *(const bf16x8*)(h2buf + ((size_t)i * 512 + bt * 16 + l15) * 128 +
                                  ks * 32 + q * 8);
    #pragma unroll 4
    for (int nt = 0; nt < 16; nt++) {
        f32x4 e4 = {0, 0, 0, 0}, o4 = {0, 0, 0, 0};
        #pragma unroll
        for (int ks = 0; ks < 4; ks += 2) {
            bf16x8 b0 = *(const bf16x8*)(wsbf + ELOFF_W3 + (size_t)i * 32768 +
                                         ((nt * 4 + ks) * 64 + lane) * 8);
            bf16x8 b1 = *(const bf16x8*)(wsbf + ELOFF_W3 + (size_t)i * 32768 +
                                         ((nt * 4 + ks + 1) * 64 + lane) * 8);
            e4 = MFMA16(af[ks], b0, e4);
            o4 = MFMA16(af[ks + 1], b1, o4);
        }
        f32x4 a = e4 + o4;
        float bv = mb3[i * 256 + nt * 16 + l15];
        #pragma unroll
        for (int rr = 0; rr < 4; rr++) {
            int b = bt * 16 + q * 4 + rr;
            size_t o = ((size_t)b * 32 + i) * 256 + nt * 16 + l15;
            outp[o] = a[rr] + bv + outp[o];
        }
    }
}

extern "C" void kernel_launch(void* const* d_in, const int* in_sizes, int n_in,
                              void* d_out, int out_size, void* d_ws, size_t ws_size,
                              hipStream_t stream) {
    (void)in_sizes; (void)n_in; (void)out_size; (void)ws_size;
    const float* noise = (const float*)d_in[0];
    const float* edge  = (const float*)d_in[1];
    const float* emb   = (const float*)d_in[2];
    const float* paW   = (const float*)d_in[3];
    const float* pab   = (const float*)d_in[4];
    const float* mW1   = (const float*)d_in[5];
    const float* mb1   = (const float*)d_in[6];
    const float* mW2   = (const float*)d_in[7];
    const float* mb2   = (const float*)d_in[8];
    const float* mW3   = (const float*)d_in[9];
    const float* mb3   = (const float*)d_in[10];
    const float* neW   = (const float*)d_in[11];
    const float* neb   = (const float*)d_in[12];
    float* outp = (float*)d_out;

    unsigned short* adjb = (unsigned short*)((char*)d_ws + WS_ADJB);
    float* b3P  = (float*)((char*)d_ws + WS_B3P);
    float* embP = (float*)((char*)d_ws + WS_EMBP);
    unsigned short* wsb  = (unsigned short*)((char*)d_ws + WS_WSB);
    unsigned short* h2b  = (unsigned short*)((char*)d_ws + WS_H2B);

    prep_all<<<2121, 256, 0, stream>>>(paW, mW1, mW2, mW3, edge, wsb, adjb,
                                       noise, neW, neb, outp, mb3, emb, pab,
                                       b3P, embP);
    scm_main<<<NBLK, 512, 0, stream>>>(embP, b3P, mb1, mb2, adjb,
                                       (const __bf16*)wsb, outp, h2b);
    post_out<<<256, 256, 0, stream>>>(h2b, (const __bf16*)wsb, mb3, outp);
}

// Round 8
// 393.056 us; speedup vs baseline: 1.3083x; 1.0092x over previous
//
#include <hip/hip_runtime.h>

// ---------------------------------------------------------------------------
// StructuralCausalModel: 3 layers x 32 vars sequential scan, BATCH=512.
// R15: R14 (ne2S-in-LDS prologue, h2buf+post_out, 3 barriers/step) +
// FULL weight ping/pong under __launch_bounds__(512,2): w1/w2/wP0/wP1 all
// double-buffered in named register sets (~160 VGPR of landing zone), so
// every weight load has a full step of in-flight cover AND reserved
// registers (R13 tried this at a 128-VGPR cap and churned; R14's VGPR=92
// shows the compiler won't keep loads in flight without forced landing regs).
// LDS 151.9 KB -> 1 block/CU -> 8 waves -> 2/SIMD -> 256-VGPR budget.
// ---------------------------------------------------------------------------

typedef __bf16 bf16x8 __attribute__((ext_vector_type(8)));
typedef float  f32x4  __attribute__((ext_vector_type(4)));

#define N_VARS 32
#define BTILE 4
#define NBLK 128

// ---- ws byte offsets ----
#define WS_ADJB   0            // ushort[32*64]  (4 KB)
#define WS_B3P    4096         // float [32*256] (32 KB)
#define WS_EMBP   36864        // float [32*256] (32 KB)
#define WS_WSB    69632        // bf16 weight-fragment base
// element offsets within wsb (ushort elements)
#define ELOFF_PA  0
#define ELOFF_W1  65536
#define ELOFF_W2  1114112
#define ELOFF_W3  1638400
#define ELOFF_W3P 2686976
// wsb total el = 3735552 -> 7471104 B; ends at 69632+7471104 = 7540736
#define WS_H2B    7540736      // ushort[32*512*128] = 4 MB (h2 of last layer)
// total ws < 16 MB

// LDS row strides (ushorts).
#define XSTR 272
#define HSTR 144
#define VSTR 40    // valsP col stride (80 B): b128 frag reads 16B-aligned

__device__ __forceinline__ unsigned short f2b(float f) {
    unsigned u = __float_as_uint(f);
    u += 0x7FFFu + ((u >> 16) & 1u);
    return (unsigned short)(u >> 16);
}

__device__ __forceinline__ float b2f(unsigned short u) {
    return __uint_as_float(((unsigned)u) << 16);
}

// lgkm-only barrier: LDS ordering enforced, global loads stay in flight.
__device__ __forceinline__ void bar_lds() {
    asm volatile("s_waitcnt lgkmcnt(0)\n\ts_barrier" ::: "memory");
}

// erf via Abramowitz-Stegun 7.1.25, 3 terms (|err| <= 2.5e-5)
__device__ __forceinline__ float gelu_e(float x) {
    float z  = x * 0.7071067811865476f;
    float az = fabsf(z);
    float t  = __builtin_amdgcn_rcpf(1.0f + 0.47047f * az);
    float p  = t * (0.3480242f + t * (-0.0958798f + t * 0.7478556f));
    float e  = 1.0f - p * __expf(-z * z);
    float er = (z < 0.0f) ? -e : e;
    return 0.5f * x * (1.0f + er);
}

// Extract element q (q = lane>>4, runtime) via compile-time-indexed selects.
__device__ __forceinline__ float pickq(f32x4 v, int q) {
    float lo = (q & 1) ? v[1] : v[0];
    float hi = (q & 1) ? v[3] : v[2];
    return (q & 2) ? hi : lo;
}

#define MFMA16(a, b, c) __builtin_amdgcn_mfma_f32_16x16x32_bf16(a, b, c, 0, 0, 0)

// ---------------------------------------------------------------------------
// prep_all (2121 blocks x 256):
//  [0,520):     weight swizzle via LDS tile (PA, W1, W2, W3)
//  520:         adjacency (bf16 hi/lo)
//  [521,1545):  noise encoder NE -> outp
//  [1545,2057): W3P = W3@paW compute (f32) + DIRECT swizzled bf16 write
//  [2057,2089): b3P = b3@paW
//  [2089,2121): embP = emb@paW + pab
// B-frag (16x16x32): lane l, elem j -> k = ks*32+(l>>4)*8+j, n = nt*16+(l&15)
// ---------------------------------------------------------------------------
__global__ void prep_all(const float* __restrict__ paW, const float* __restrict__ mW1,
                         const float* __restrict__ mW2, const float* __restrict__ mW3,
                         const float* __restrict__ edge, unsigned short* __restrict__ wsb,
                         unsigned short* __restrict__ adjb,
                         const float* __restrict__ noise, const float* __restrict__ neW,
                         const float* __restrict__ neb, float* __restrict__ outp,
                         const float* __restrict__ mb3, const float* __restrict__ emb,
                         const float* __restrict__ pab,
                         float* __restrict__ b3P, float* __restrict__ embP) {
    __shared__ unsigned short tile[32 * 256];
    const int c = blockIdx.x, tid = threadIdx.x;
    if (c < 520) {
        const float* src; unsigned short* dst; int N, KS, ks;
        if (c < 8)        { src = paW;                     dst = wsb + ELOFF_PA;             N = 256; KS = 8; ks = c; }
        else if (c < 264) { int v = (c - 8) >> 3;   ks = (c - 8) & 7;
                            src = mW1 + v * 32768;         dst = wsb + ELOFF_W1 + v * 32768; N = 128; KS = 8; }
        else if (c < 392) { int v = (c - 264) >> 2; ks = (c - 264) & 3;
                            src = mW2 + v * 16384;         dst = wsb + ELOFF_W2 + v * 16384; N = 128; KS = 4; }
        else              { int v = (c - 392) >> 2; ks = (c - 392) & 3;
                            src = mW3 + v * 32768;         dst = wsb + ELOFF_W3 + v * 32768; N = 256; KS = 4; }
        const int kb = ks * 32, nsh = (N == 256) ? 8 : 7;
        for (int t = tid; t < 32 * N; t += 256) {
            int r = t >> nsh, col = t & (N - 1);
            tile[r * N + col] = f2b(src[(kb + r) * N + col]);   // coalesced in col
        }
        __syncthreads();
        const int nout = (N >> 4) * 64;
        for (int o = tid; o < nout; o += 256) {
            int nt = o >> 6, lane = o & 63;
            int n = nt * 16 + (lane & 15), k0 = (lane >> 4) << 3;
            unsigned e[8];
            #pragma unroll
            for (int j = 0; j < 8; j++) e[j] = tile[(k0 + j) * N + n];
            uint4 pk;
            pk.x = e[0] | (e[1] << 16); pk.y = e[2] | (e[3] << 16);
            pk.z = e[4] | (e[5] << 16); pk.w = e[6] | (e[7] << 16);
            *(uint4*)(dst + ((nt * KS + ks) * 64 + lane) * 8) = pk;   // coalesced
        }
    } else if (c == 520) {
        for (int t = tid; t < 1024; t += 256) {
            int v = t >> 5, ci = t & 31;
            float x = edge[t];
            float m = (v == ci) ? 0.0f : x;   // diag logit masked -> adj diag = 0.5
            float a = __builtin_amdgcn_rcpf(1.0f + __expf(-2.0f * m));
            unsigned short hi = f2b(a);
            float rem = a - b2f(hi);
            adjb[ci * 64 + v]      = hi;        // row ci: parents-of-ci weights
            adjb[ci * 64 + 32 + v] = f2b(rem);  // low part (an ~ 16-bit mantissa)
        }
    } else if (c < 1545) {
        int sb = c - 521;                     // 1024 sub-blocks: 32 vars x 32 groups
        int i = sb >> 5, g = sb & 31, d = tid;
        float w[64];
        #pragma unroll
        for (int k = 0; k < 64; k++) w[k] = neW[(i * 64 + k) * 256 + d];
        float bias = neb[i * 256 + d];
        for (int bb = 0; bb < 16; bb++) {
            int b = g * 16 + bb;
            const float* nr = noise + (b * 32 + i) * 64;
            float a0 = bias, a1 = 0.f, a2 = 0.f, a3 = 0.f;
            #pragma unroll
            for (int k = 0; k < 16; k++) {      // 4 independent fma chains
                a0 += nr[4 * k + 0] * w[4 * k + 0];
                a1 += nr[4 * k + 1] * w[4 * k + 1];
                a2 += nr[4 * k + 2] * w[4 * k + 2];
                a3 += nr[4 * k + 3] * w[4 * k + 3];
            }
            outp[(b * 32 + i) * 256 + d] = gelu_e((a0 + a1) + (a2 + a3));
        }
    } else if (c < 2057) {
        // W3P[v][m][d] = sum_n W3[v][m][n]*paW[n][d]; one m-octet per block,
        // written DIRECTLY in swizzled B-frag layout (k-octet = m-octet).
        const int idx = c - 1545;
        const int v = idx >> 4, mg = (idx & 15) * 8;
        const int d = tid;
        const float* w3r = mW3 + (size_t)(v * 128 + mg) * 256;
        float acc[8];
        #pragma unroll
        for (int r = 0; r < 8; r++) acc[r] = 0.f;
        for (int n = 0; n < 256; n++) {
            float pa = paW[n * 256 + d];          // coalesced; w3r wave-uniform
            #pragma unroll
            for (int r = 0; r < 8; r++) acc[r] += w3r[r * 256 + n] * pa;
        }
        const int ks = mg >> 5, lg = (mg >> 3) & 3;
        const int nt = d >> 4, lane = lg * 16 + (d & 15);
        uint4 pk;
        pk.x = (unsigned)f2b(acc[0]) | ((unsigned)f2b(acc[1]) << 16);
        pk.y = (unsigned)f2b(acc[2]) | ((unsigned)f2b(acc[3]) << 16);
        pk.z = (unsigned)f2b(acc[4]) | ((unsigned)f2b(acc[5]) << 16);
        pk.w = (unsigned)f2b(acc[6]) | ((unsigned)f2b(acc[7]) << 16);
        *(uint4*)(wsb + ELOFF_W3P + v * 32768 + ((nt * 4 + ks) * 64 + lane) * 8) = pk;
    } else if (c < 2089) {
        const int v = c - 2057;
        float a = 0.f;
        for (int n = 0; n < 256; n++) a += mb3[v * 256 + n] * paW[n * 256 + tid];
        b3P[v * 256 + tid] = a;
    } else {
        const int v = c - 2089;
        float a = pab[tid];
        for (int n = 0; n < 256; n++) a += emb[v * 256 + n] * paW[n * 256 + tid];
        embP[v * 256 + tid] = a;
    }
}

// ---------------------------------------------------------------------------
// Main: 128 blocks x 512 threads, launch_bounds(512,2) -> 256 VGPR budget.
// Prologue: NE2 = NE@paW per block via MFMA into LDS ne2S (64 KB).
// Per step (3 barriers): full ping/pong weight sets (prefetch next at top).
// B: W1 -> Hs1.  C: W2 + pcP(inline-reduced) -> Hs2 (+h2buf, last layer).
// D: W3P -> valsP[i]; lane-local fixup + gelu -> X2.
// ---------------------------------------------------------------------------
__global__ __launch_bounds__(512, 2) void
scm_main(const float* __restrict__ embP, const float* __restrict__ b3Pp,
         const float* __restrict__ mb1, const float* __restrict__ mb2,
         const unsigned short* __restrict__ adjb,
         const __bf16* __restrict__ wsbf, const float* __restrict__ outp,
         unsigned short* __restrict__ h2buf) {
    __shared__ unsigned short valsP[1024 * VSTR];   // 80 KB
    __shared__ unsigned short ne2S[4 * 32 * 256];   // 64 KB  [(b-row*32+i)*256+d]
    __shared__ unsigned short X2[4 * XSTR];
    __shared__ unsigned short Hs1[4 * HSTR];
    __shared__ unsigned short Hs2[4 * HSTR];

    const int tid = threadIdx.x, blk = blockIdx.x;

    {   // zero valsP (1024*40 ushorts = 5120 uint4)
        uint4 z; z.x = z.y = z.z = z.w = 0;
        for (int k = tid; k < 5120; k += 512) ((uint4*)valsP)[k] = z;
    }

    const int wid = tid >> 6, lane = tid & 63, l15 = lane & 15, q = lane >> 4;
    const int l3 = l15 & 3;                 // A-frag row (BTILE=4; rows alias)
    const int nW = wid * 16 + l15;
    const int n0 = nW, n1 = nW + 128;

    // ---- prologue: ne2S[(r*32+i)*256+d] = (NE @ paW)[blk*4+r, i, d] ----
    {
        const int R = wid * 16 + l15;               // row id: r=R>>5, i=R&31
        const float* src = outp + ((size_t)(blk * BTILE + (R >> 5)) * 32 + (R & 31)) * 256 + q * 8;
        bf16x8 afr[8];
        #pragma unroll
        for (int ks = 0; ks < 8; ks++) {
            float4 x0 = *(const float4*)(src + ks * 32);
            float4 x1 = *(const float4*)(src + ks * 32 + 4);
            uint4 pk;
            pk.x = (unsigned)f2b(x0.x) | ((unsigned)f2b(x0.y) << 16);
            pk.y = (unsigned)f2b(x0.z) | ((unsigned)f2b(x0.w) << 16);
            pk.z = (unsigned)f2b(x1.x) | ((unsigned)f2b(x1.y) << 16);
            pk.w = (unsigned)f2b(x1.z) | ((unsigned)f2b(x1.w) << 16);
            afr[ks] = __builtin_bit_cast(bf16x8, pk);
        }
        #pragma unroll 4
        for (int nt = 0; nt < 16; nt++) {
            f32x4 e4 = {0, 0, 0, 0}, o4 = {0, 0, 0, 0};
            #pragma unroll
            for (int ks = 0; ks < 8; ks += 2) {
                bf16x8 b0 = *(const bf16x8*)(wsbf + ELOFF_PA + ((nt * 8 + ks) * 64 + lane) * 8);
                bf16x8 b1 = *(const bf16x8*)(wsbf + ELOFF_PA + ((nt * 8 + ks + 1) * 64 + lane) * 8);
                e4 = MFMA16(afr[ks], b0, e4);
                o4 = MFMA16(afr[ks + 1], b1, o4);
            }
            f32x4 a = e4 + o4;
            #pragma unroll
            for (int rr = 0; rr < 4; rr++) {
                int R2 = wid * 16 + q * 4 + rr;     // (r2*32+i2) packed
                ne2S[R2 * 256 + nt * 16 + l15] = f2b(a[rr]);
            }
        }
    }

    // seed X2 for step 0: valsP = 0 -> pcP = 0 -> X2 = gelu(embP'_0)
    X2[q * XSTR + n0] = f2b(gelu_e(embP[n0]));
    X2[q * XSTR + n1] = f2b(gelu_e(embP[n1]));
    bar_lds();

    // ---- full ping/pong weight fragment sets (named; no dynamic indexing) ----
    bf16x8 wa1[8], wa2[4], waP0[4], waP1[4];
    bf16x8 wb1[8], wb2[4], wbP0[4], wbP1[4];

    auto loadw = [&](int i, bf16x8 (&w1)[8], bf16x8 (&w2)[4],
                     bf16x8 (&wP0)[4], bf16x8 (&wP1)[4]) {
        #pragma unroll
        for (int ks = 0; ks < 8; ks++)
            w1[ks] = *(const bf16x8*)(wsbf + ELOFF_W1 + (size_t)i * 32768 +
                                      ((wid * 8 + ks) * 64 + lane) * 8);
        #pragma unroll
        for (int ks = 0; ks < 4; ks++) {
            w2[ks]  = *(const bf16x8*)(wsbf + ELOFF_W2 + (size_t)i * 16384 +
                                       ((wid * 4 + ks) * 64 + lane) * 8);
            wP0[ks] = *(const bf16x8*)(wsbf + ELOFF_W3P + (size_t)i * 32768 +
                                       ((wid * 4 + ks) * 64 + lane) * 8);
            wP1[ks] = *(const bf16x8*)(wsbf + ELOFF_W3P + (size_t)i * 32768 +
                                       (((wid + 8) * 4 + ks) * 64 + lane) * 8);
        }
    };

    auto step = [&](int s, bf16x8 (&w1f)[8], bf16x8 (&w2f)[4],
                    bf16x8 (&wPf0)[4], bf16x8 (&wPf1)[4],
                    bf16x8 (&x1)[8], bf16x8 (&x2)[4],
                    bf16x8 (&xP0)[4], bf16x8 (&xP1)[4]) {
        const int i = s & 31, ni = (s + 1) & 31;
        const bool last = s >= 64;

        // ---- prefetch NEXT step's full weight set (consumed next step) ----
        loadw(ni, x1, x2, xP0, xP1);

        // ---- per-step scalars ----
        float bi1 = mb1[i * 128 + nW];
        float bi2 = mb2[i * 128 + nW];
        const float ne2_0 = b2f(ne2S[(q * 32 + i) * 256 + n0]);
        const float ne2_1 = b2f(ne2S[(q * 32 + i) * 256 + n1]);
        const float b3P0 = b3Pp[i * 256 + n0];
        const float b3P1 = b3Pp[i * 256 + n1];
        const float eP0 = embP[ni * 256 + n0];
        const float eP1 = embP[ni * 256 + n1];
        bf16x8 anh = *(const bf16x8*)(adjb + ni * 64 + q * 8);
        bf16x8 anl = *(const bf16x8*)(adjb + ni * 64 + 32 + q * 8);
        const float ani = b2f(adjb[ni * 64 + i]) + b2f(adjb[ni * 64 + 32 + i]);

        // ==== B: W1 GEMM on X2 -> Hs1 ====
        {
            f32x4 aa = {0, 0, 0, 0}, ab = {0, 0, 0, 0};
            f32x4 ac = {0, 0, 0, 0}, ad = {0, 0, 0, 0};
            #pragma unroll
            for (int ks = 0; ks < 8; ks += 4) {
                bf16x8 af0 = *(const bf16x8*)(X2 + l3 * XSTR + ks * 32 + q * 8);
                bf16x8 af1 = *(const bf16x8*)(X2 + l3 * XSTR + (ks + 1) * 32 + q * 8);
                bf16x8 af2 = *(const bf16x8*)(X2 + l3 * XSTR + (ks + 2) * 32 + q * 8);
                bf16x8 af3 = *(const bf16x8*)(X2 + l3 * XSTR + (ks + 3) * 32 + q * 8);
                aa = MFMA16(af0, w1f[ks], aa);
                ab = MFMA16(af1, w1f[ks + 1], ab);
                ac = MFMA16(af2, w1f[ks + 2], ac);
                ad = MFMA16(af3, w1f[ks + 3], ad);
            }
            float sb = (pickq(aa, q) + pickq(ab, q)) +
                       (pickq(ac, q) + pickq(ad, q)) + bi1;
            Hs1[q * HSTR + nW] = f2b(gelu_e(sb));
        }
        bar_lds();

        // ==== C: W2 GEMM; pcP GEMM (inline-reduced); snap old; h2 store ====
        float pc0 = 0.f, pc1 = 0.f, oP0, oP1;
        {
            f32x4 ca = {0, 0, 0, 0}, cb = {0, 0, 0, 0};
            #pragma unroll
            for (int ks = 0; ks < 4; ks += 2) {
                bf16x8 af0 = *(const bf16x8*)(Hs1 + l3 * HSTR + ks * 32 + q * 8);
                bf16x8 af1 = *(const bf16x8*)(Hs1 + l3 * HSTR + (ks + 1) * 32 + q * 8);
                ca = MFMA16(af0, w2f[ks], ca);
                cb = MFMA16(af1, w2f[ks + 1], cb);
            }
            // pcP: K=32 tile per b=t; all C rows identical (A rows = an);
            // lane keeps only its own tile's element [0].
            #pragma unroll
            for (int t = 0; t < 4; t++) {
                bf16x8 vf0 = *(const bf16x8*)(valsP + (t * 256 + n0) * VSTR + q * 8);
                bf16x8 vf1 = *(const bf16x8*)(valsP + (t * 256 + n1) * VSTR + q * 8);
                f32x4 z = {0, 0, 0, 0};
                f32x4 p0 = MFMA16(anl, vf0, MFMA16(anh, vf0, z));
                f32x4 p1 = MFMA16(anl, vf1, MFMA16(anh, vf1, z));
                pc0 = (q == t) ? p0[0] : pc0;
                pc1 = (q == t) ? p1[0] : pc1;
            }
            oP0 = b2f(valsP[(q * 256 + n0) * VSTR + i]);
            oP1 = b2f(valsP[(q * 256 + n1) * VSTR + i]);
            float scv = pickq(ca, q) + pickq(cb, q) + bi2;
            unsigned short hv = f2b(gelu_e(scv));
            Hs2[q * HSTR + nW] = hv;
            if (last)
                h2buf[((size_t)i * 512 + blk * BTILE + q) * 128 + nW] = hv;
        }
        bar_lds();

        // ==== D: W3P GEMM -> valsP[i]; lane-local fixup + gelu -> X2 ====
        {
            f32x4 c0a = {0, 0, 0, 0}, c0b = {0, 0, 0, 0};
            f32x4 c1a = {0, 0, 0, 0}, c1b = {0, 0, 0, 0};
            #pragma unroll
            for (int ks = 0; ks < 4; ks += 2) {
                bf16x8 af0 = *(const bf16x8*)(Hs2 + l3 * HSTR + ks * 32 + q * 8);
                bf16x8 af1 = *(const bf16x8*)(Hs2 + l3 * HSTR + (ks + 1) * 32 + q * 8);
                c0a = MFMA16(af0, wPf0[ks], c0a);
                c1a = MFMA16(af0, wPf1[ks], c1a);
                c0b = MFMA16(af1, wPf0[ks + 1], c0b);
                c1b = MFMA16(af1, wPf1[ks + 1], c1b);
            }
            float nP0 = pickq(c0a, q) + pickq(c0b, q) + b3P0 + ne2_0;
            float nP1 = pickq(c1a, q) + pickq(c1b, q) + b3P1 + ne2_1;
            unsigned short ur0 = f2b(nP0), ur1 = f2b(nP1);
            valsP[(q * 256 + n0) * VSTR + i] = ur0;
            valsP[(q * 256 + n1) * VSTR + i] = ur1;
            float x0 = pc0 + ani * (b2f(ur0) - oP0) + eP0;
            float x1 = pc1 + ani * (b2f(ur1) - oP1) + eP1;
            X2[q * XSTR + n0] = f2b(gelu_e(x0));
            X2[q * XSTR + n1] = f2b(gelu_e(x1));
        }
        bar_lds();
    };

    loadw(0, wa1, wa2, waP0, waP1);
    for (int ss = 0; ss < 48; ss++) {
        step(2 * ss,     wa1, wa2, waP0, waP1, wb1, wb2, wbP0, wbP1);
        step(2 * ss + 1, wb1, wb2, wbP0, wbP1, wa1, wa2, waP0, waP1);
    }
}

// ---------------------------------------------------------------------------
// post_out (256 blocks x 256): outp = h2 @ W3 + b3 + ne  (ne already in outp).
// Wave gid in [0,1024): i = gid>>5, bt = gid&31 -> rows b = bt*16..+15.
// ---------------------------------------------------------------------------
__global__ __launch_bounds__(256) void
post_out(const unsigned short* __restrict__ h2buf, const __bf16* __restrict__ wsbf,
         const float* __restrict__ mb3, float* __restrict__ outp) {
    const int tid = threadIdx.x;
    const int wid = tid >> 6, lane = tid & 63, l15 = lane & 15, q = lane >> 4;
    const int gid = blockIdx.x * 4 + wid;
    const int i = gid >> 5, bt = gid & 31;
    bf16x8 af[4];
    #pragma unroll
    for (int ks = 0; ks < 4; ks++)
        af[ks] = *(const bf16x8*)(h2buf + ((size_t)i * 512 + bt * 16 + l15) * 128 +
                                  ks * 32 + q * 8);
    #pragma unroll 4
    for (int nt = 0; nt < 16; nt++) {
        f32x4 e4 = {0, 0, 0, 0}, o4 = {0, 0, 0, 0};
        #pragma unroll
        for (int ks = 0; ks < 4; ks += 2) {
            bf16x8 b0 = *(const bf16x8*)(wsbf + ELOFF_W3 + (size_t)i * 32768 +
                                         ((nt * 4 + ks) * 64 + lane) * 8);
            bf16x8 b1 = *(const bf16x8*)(wsbf + ELOFF_W3 + (size_t)i * 32768 +
                                         ((nt * 4 + ks + 1) * 64 + lane) * 8);
            e4 = MFMA16(af[ks], b0, e4);
            o4 = MFMA16(af[ks + 1], b1, o4);
        }
        f32x4 a = e4 + o4;
        float bv = mb3[i * 256 + nt * 16 + l15];
        #pragma unroll
        for (int rr = 0; rr < 4; rr++) {
            int b = bt * 16 + q * 4 + rr;
            size_t o = ((size_t)b * 32 + i) * 256 + nt * 16 + l15;
            outp[o] = a[rr] + bv + outp[o];
        }
    }
}

extern "C" void kernel_launch(void* const* d_in, const int* in_sizes, int n_in,
                              void* d_out, int out_size, void* d_ws, size_t ws_size,
                              hipStream_t stream) {
    (void)in_sizes; (void)n_in; (void)out_size; (void)ws_size;
    const float* noise = (const float*)d_in[0];
    const float* edge  = (const float*)d_in[1];
    const float* emb   = (const float*)d_in[2];
    const float* paW   = (const float*)d_in[3];
    const float* pab   = (const float*)d_in[4];
    const float* mW1   = (const float*)d_in[5];
    const float* mb1   = (const float*)d_in[6];
    const float* mW2   = (const float*)d_in[7];
    const float* mb2   = (const float*)d_in[8];
    const float* mW3   = (const float*)d_in[9];
    const float* mb3   = (const float*)d_in[10];
    const float* neW   = (const float*)d_in[11];
    const float* neb   = (const float*)d_in[12];
    float* outp = (float*)d_out;

    unsigned short* adjb = (unsigned short*)((char*)d_ws + WS_ADJB);
    float* b3P  = (float*)((char*)d_ws + WS_B3P);
    float* embP = (float*)((char*)d_ws + WS_EMBP);
    unsigned short* wsb  = (unsigned short*)((char*)d_ws + WS_WSB);
    unsigned short* h2b  = (unsigned short*)((char*)d_ws + WS_H2B);

    prep_all<<<2121, 256, 0, stream>>>(paW, mW1, mW2, mW3, edge, wsb, adjb,
                                       noise, neW, neb, outp, mb3, emb, pab,
                                       b3P, embP);
    scm_main<<<NBLK, 512, 0, stream>>>(embP, b3P, mb1, mb2, adjb,
                                       (const __bf16*)wsb, outp, h2b);
    post_out<<<256, 256, 0, stream>>>(h2b, (const __bf16*)wsb, mb3, outp);
}

// Round 9
// 386.435 us; speedup vs baseline: 1.3307x; 1.0171x over previous
//
#include <hip/hip_runtime.h>

// ---------------------------------------------------------------------------
// StructuralCausalModel: 3 layers x 32 vars sequential scan, BATCH=512.
// R16: R15 structure, but the cross-step prefetch is INLINE-ASM controlled:
//  - all 24 per-step global loads (20 weight b128 + bi1/bi2/eP0/eP1) issued
//    via asm global_load_* into a named WSet struct (forced landing regs),
//    one set ahead; single counted s_waitcnt vmcnt(24) + sched_barrier(0)
//    at step top (retires set(s), leaves set(s+1) in flight a full step).
//  - zero compiler VMEM loads in the loop (their auto-waits would drain us):
//    b3P folded into ne2S at prologue; adjacency copied to LDS adjS (+4KB);
//    ani/anh/anl are ds_reads. Last-layer h2 store stays compiler-emitted
//    (stores need no waits; vmcnt(24) math retires it safely).
// LDS 152.4 KB (1 block/CU, 8 waves, 2/SIMD -> 256 VGPR budget via
// __launch_bounds__(512,2)).
// ---------------------------------------------------------------------------

typedef __bf16 bf16x8 __attribute__((ext_vector_type(8)));
typedef float  f32x4  __attribute__((ext_vector_type(4)));

#define N_VARS 32
#define BTILE 4
#define NBLK 128

// ---- ws byte offsets ----
#define WS_ADJB   0            // ushort[32*64]  (4 KB)
#define WS_B3P    4096         // float [32*256] (32 KB)
#define WS_EMBP   36864        // float [32*256] (32 KB)
#define WS_WSB    69632        // bf16 weight-fragment base
// element offsets within wsb (ushort elements)
#define ELOFF_PA  0
#define ELOFF_W1  65536
#define ELOFF_W2  1114112
#define ELOFF_W3  1638400
#define ELOFF_W3P 2686976
// wsb total el = 3735552 -> 7471104 B; ends at 69632+7471104 = 7540736
#define WS_H2B    7540736      // ushort[32*512*128] = 4 MB (h2 of last layer)
// total ws < 16 MB

// LDS row strides (ushorts).
#define XSTR 272
#define HSTR 144
#define VSTR 40    // valsP col stride (80 B): b128 frag reads 16B-aligned

__device__ __forceinline__ unsigned short f2b(float f) {
    unsigned u = __float_as_uint(f);
    u += 0x7FFFu + ((u >> 16) & 1u);
    return (unsigned short)(u >> 16);
}

__device__ __forceinline__ float b2f(unsigned short u) {
    return __uint_as_float(((unsigned)u) << 16);
}

// lgkm-only barrier: LDS ordering enforced, global (vmcnt) loads stay in flight.
__device__ __forceinline__ void bar_lds() {
    asm volatile("s_waitcnt lgkmcnt(0)\n\ts_barrier" ::: "memory");
}

// erf via Abramowitz-Stegun 7.1.25, 3 terms (|err| <= 2.5e-5)
__device__ __forceinline__ float gelu_e(float x) {
    float z  = x * 0.7071067811865476f;
    float az = fabsf(z);
    float t  = __builtin_amdgcn_rcpf(1.0f + 0.47047f * az);
    float p  = t * (0.3480242f + t * (-0.0958798f + t * 0.7478556f));
    float e  = 1.0f - p * __expf(-z * z);
    float er = (z < 0.0f) ? -e : e;
    return 0.5f * x * (1.0f + er);
}

// Extract element q (q = lane>>4, runtime) via compile-time-indexed selects.
__device__ __forceinline__ float pickq(f32x4 v, int q) {
    float lo = (q & 1) ? v[1] : v[0];
    float hi = (q & 1) ? v[3] : v[2];
    return (q & 2) ? hi : lo;
}

#define MFMA16(a, b, c) __builtin_amdgcn_mfma_f32_16x16x32_bf16(a, b, c, 0, 0, 0)

// asm loads with forced VGPR landing zones (compiler cannot sink/free these)
#define GLD4(dst, ptr) asm volatile("global_load_dwordx4 %0, %1, off" \
                                    : "=v"(dst) : "v"(ptr))
#define GLD1(dst, ptr) asm volatile("global_load_dword %0, %1, off" \
                                    : "=v"(dst) : "v"(ptr))

// ---------------------------------------------------------------------------
// prep_all (2121 blocks x 256):
//  [0,520):     weight swizzle via LDS tile (PA, W1, W2, W3)
//  520:         adjacency (bf16 hi/lo)
//  [521,1545):  noise encoder NE -> outp
//  [1545,2057): W3P = W3@paW compute (f32) + DIRECT swizzled bf16 write
//  [2057,2089): b3P = b3@paW
//  [2089,2121): embP = emb@paW + pab
// B-frag (16x16x32): lane l, elem j -> k = ks*32+(l>>4)*8+j, n = nt*16+(l&15)
// ---------------------------------------------------------------------------
__global__ void prep_all(const float* __restrict__ paW, const float* __restrict__ mW1,
                         const float* __restrict__ mW2, const float* __restrict__ mW3,
                         const float* __restrict__ edge, unsigned short* __restrict__ wsb,
                         unsigned short* __restrict__ adjb,
                         const float* __restrict__ noise, const float* __restrict__ neW,
                         const float* __restrict__ neb, float* __restrict__ outp,
                         const float* __restrict__ mb3, const float* __restrict__ emb,
                         const float* __restrict__ pab,
                         float* __restrict__ b3P, float* __restrict__ embP) {
    __shared__ unsigned short tile[32 * 256];
    const int c = blockIdx.x, tid = threadIdx.x;
    if (c < 520) {
        const float* src; unsigned short* dst; int N, KS, ks;
        if (c < 8)        { src = paW;                     dst = wsb + ELOFF_PA;             N = 256; KS = 8; ks = c; }
        else if (c < 264) { int v = (c - 8) >> 3;   ks = (c - 8) & 7;
                            src = mW1 + v * 32768;         dst = wsb + ELOFF_W1 + v * 32768; N = 128; KS = 8; }
        else if (c < 392) { int v = (c - 264) >> 2; ks = (c - 264) & 3;
                            src = mW2 + v * 16384;         dst = wsb + ELOFF_W2 + v * 16384; N = 128; KS = 4; }
        else              { int v = (c - 392) >> 2; ks = (c - 392) & 3;
                            src = mW3 + v * 32768;         dst = wsb + ELOFF_W3 + v * 32768; N = 256; KS = 4; }
        const int kb = ks * 32, nsh = (N == 256) ? 8 : 7;
        for (int t = tid; t < 32 * N; t += 256) {
            int r = t >> nsh, col = t & (N - 1);
            tile[r * N + col] = f2b(src[(kb + r) * N + col]);   // coalesced in col
        }
        __syncthreads();
        const int nout = (N >> 4) * 64;
        for (int o = tid; o < nout; o += 256) {
            int nt = o >> 6, lane = o & 63;
            int n = nt * 16 + (lane & 15), k0 = (lane >> 4) << 3;
            unsigned e[8];
            #pragma unroll
            for (int j = 0; j < 8; j++) e[j] = tile[(k0 + j) * N + n];
            uint4 pk;
            pk.x = e[0] | (e[1] << 16); pk.y = e[2] | (e[3] << 16);
            pk.z = e[4] | (e[5] << 16); pk.w = e[6] | (e[7] << 16);
            *(uint4*)(dst + ((nt * KS + ks) * 64 + lane) * 8) = pk;   // coalesced
        }
    } else if (c == 520) {
        for (int t = tid; t < 1024; t += 256) {
            int v = t >> 5, ci = t & 31;
            float x = edge[t];
            float m = (v == ci) ? 0.0f : x;   // diag logit masked -> adj diag = 0.5
            float a = __builtin_amdgcn_rcpf(1.0f + __expf(-2.0f * m));
            unsigned short hi = f2b(a);
            float rem = a - b2f(hi);
            adjb[ci * 64 + v]      = hi;        // row ci: parents-of-ci weights
            adjb[ci * 64 + 32 + v] = f2b(rem);  // low part (an ~ 16-bit mantissa)
        }
    } else if (c < 1545) {
        int sb = c - 521;                     // 1024 sub-blocks: 32 vars x 32 groups
        int i = sb >> 5, g = sb & 31, d = tid;
        float w[64];
        #pragma unroll
        for (int k = 0; k < 64; k++) w[k] = neW[(i * 64 + k) * 256 + d];
        float bias = neb[i * 256 + d];
        for (int bb = 0; bb < 16; bb++) {
            int b = g * 16 + bb;
            const float* nr = noise + (b * 32 + i) * 64;
            float a0 = bias, a1 = 0.f, a2 = 0.f, a3 = 0.f;
            #pragma unroll
            for (int k = 0; k < 16; k++) {      // 4 independent fma chains
                a0 += nr[4 * k + 0] * w[4 * k + 0];
                a1 += nr[4 * k + 1] * w[4 * k + 1];
                a2 += nr[4 * k + 2] * w[4 * k + 2];
                a3 += nr[4 * k + 3] * w[4 * k + 3];
            }
            outp[(b * 32 + i) * 256 + d] = gelu_e((a0 + a1) + (a2 + a3));
        }
    } else if (c < 2057) {
        // W3P[v][m][d] = sum_n W3[v][m][n]*paW[n][d]; one m-octet per block,
        // written DIRECTLY in swizzled B-frag layout (k-octet = m-octet).
        const int idx = c - 1545;
        const int v = idx >> 4, mg = (idx & 15) * 8;
        const int d = tid;
        const float* w3r = mW3 + (size_t)(v * 128 + mg) * 256;
        float acc[8];
        #pragma unroll
        for (int r = 0; r < 8; r++) acc[r] = 0.f;
        for (int n = 0; n < 256; n++) {
            float pa = paW[n * 256 + d];          // coalesced; w3r wave-uniform
            #pragma unroll
            for (int r = 0; r < 8; r++) acc[r] += w3r[r * 256 + n] * pa;
        }
        const int ks = mg >> 5, lg = (mg >> 3) & 3;
        const int nt = d >> 4, lane = lg * 16 + (d & 15);
        uint4 pk;
        pk.x = (unsigned)f2b(acc[0]) | ((unsigned)f2b(acc[1]) << 16);
        pk.y = (unsigned)f2b(acc[2]) | ((unsigned)f2b(acc[3]) << 16);
        pk.z = (unsigned)f2b(acc[4]) | ((unsigned)f2b(acc[5]) << 16);
        pk.w = (unsigned)f2b(acc[6]) | ((unsigned)f2b(acc[7]) << 16);
        *(uint4*)(wsb + ELOFF_W3P + v * 32768 + ((nt * 4 + ks) * 64 + lane) * 8) = pk;
    } else if (c < 2089) {
        const int v = c - 2057;
        float a = 0.f;
        for (int n = 0; n < 256; n++) a += mb3[v * 256 + n] * paW[n * 256 + tid];
        b3P[v * 256 + tid] = a;
    } else {
        const int v = c - 2089;
        float a = pab[tid];
        for (int n = 0; n < 256; n++) a += emb[v * 256 + n] * paW[n * 256 + tid];
        embP[v * 256 + tid] = a;
    }
}

// ---------------------------------------------------------------------------
// Main: 128 blocks x 512 threads, launch_bounds(512,2) -> 256 VGPR budget.
// Prologue: ne2S = NE@paW + b3P (MFMA) into LDS; adjb -> LDS adjS.
// Per step: issue asm set(s+1); vmcnt(24); B: W1 -> Hs1; C: W2 + pcP -> Hs2
// (+h2buf, last layer); D: W3P -> valsP[i]; lane-local fixup + gelu -> X2.
// ---------------------------------------------------------------------------
__global__ __launch_bounds__(512, 2) void
scm_main(const float* __restrict__ embP, const float* __restrict__ b3Pp,
         const float* __restrict__ mb1, const float* __restrict__ mb2,
         const unsigned short* __restrict__ adjb,
         const __bf16* __restrict__ wsbf, const float* __restrict__ outp,
         unsigned short* __restrict__ h2buf) {
    __shared__ unsigned short valsP[1024 * VSTR];   // 80 KB
    __shared__ unsigned short ne2S[4 * 32 * 256];   // 64 KB  [(b-row*32+i)*256+d]
    __shared__ unsigned short adjS[2048];           // 4 KB   [ni][hi32,lo32]
    __shared__ unsigned short X2[4 * XSTR];
    __shared__ unsigned short Hs1[4 * HSTR];
    __shared__ unsigned short Hs2[4 * HSTR];

    const int tid = threadIdx.x, blk = blockIdx.x;

    {   // zero valsP (1024*40 ushorts = 5120 uint4); copy adjb -> adjS
        uint4 z; z.x = z.y = z.z = z.w = 0;
        for (int k = tid; k < 5120; k += 512) ((uint4*)valsP)[k] = z;
        for (int k = tid; k < 1024; k += 512)
            ((unsigned*)adjS)[k] = ((const unsigned*)adjb)[k];
    }

    const int wid = tid >> 6, lane = tid & 63, l15 = lane & 15, q = lane >> 4;
    const int l3 = l15 & 3;                 // A-frag row (BTILE=4; rows alias)
    const int nW = wid * 16 + l15;
    const int n0 = nW, n1 = nW + 128;

    // ---- prologue: ne2S[(r*32+i)*256+d] = (NE@paW)[blk*4+r,i,d] + b3P[i][d] ----
    {
        const int R = wid * 16 + l15;               // row id: r=R>>5, i=R&31
        const float* src = outp + ((size_t)(blk * BTILE + (R >> 5)) * 32 + (R & 31)) * 256 + q * 8;
        bf16x8 afr[8];
        #pragma unroll
        for (int ks = 0; ks < 8; ks++) {
            float4 x0 = *(const float4*)(src + ks * 32);
            float4 x1 = *(const float4*)(src + ks * 32 + 4);
            uint4 pk;
            pk.x = (unsigned)f2b(x0.x) | ((unsigned)f2b(x0.y) << 16);
            pk.y = (unsigned)f2b(x0.z) | ((unsigned)f2b(x0.w) << 16);
            pk.z = (unsigned)f2b(x1.x) | ((unsigned)f2b(x1.y) << 16);
            pk.w = (unsigned)f2b(x1.z) | ((unsigned)f2b(x1.w) << 16);
            afr[ks] = __builtin_bit_cast(bf16x8, pk);
        }
        #pragma unroll 4
        for (int nt = 0; nt < 16; nt++) {
            f32x4 e4 = {0, 0, 0, 0}, o4 = {0, 0, 0, 0};
            #pragma unroll
            for (int ks = 0; ks < 8; ks += 2) {
                bf16x8 b0 = *(const bf16x8*)(wsbf + ELOFF_PA + ((nt * 8 + ks) * 64 + lane) * 8);
                bf16x8 b1 = *(const bf16x8*)(wsbf + ELOFF_PA + ((nt * 8 + ks + 1) * 64 + lane) * 8);
                e4 = MFMA16(afr[ks], b0, e4);
                o4 = MFMA16(afr[ks + 1], b1, o4);
            }
            f32x4 a = e4 + o4;
            #pragma unroll
            for (int rr = 0; rr < 4; rr++) {
                int R2 = wid * 16 + q * 4 + rr;     // (r2*32+i2) packed
                ne2S[R2 * 256 + nt * 16 + l15] =
                    f2b(a[rr] + b3Pp[(R2 & 31) * 256 + nt * 16 + l15]);
            }
        }
    }

    // seed X2 for step 0: valsP = 0 -> pcP = 0 -> X2 = gelu(embP'_0)
    X2[q * XSTR + n0] = f2b(gelu_e(embP[n0]));
    X2[q * XSTR + n1] = f2b(gelu_e(embP[n1]));
    bar_lds();

    // ---- asm-prefetched per-step load set: 20 weight b128 + 4 scalars ----
    struct WSet {
        uint4 w1[8]; uint4 w2[4]; uint4 p0[4]; uint4 p1[4];
        float s0, s1, s2, s3;                 // bi1, bi2, eP0, eP1
    };

    auto issue_set = [&](WSet& S, int st) {
        const int it = st & 31, nt2 = (st + 1) & 31;
        const __bf16* b1 = wsbf + ELOFF_W1 + (size_t)it * 32768 +
                           ((size_t)(wid * 8) * 64 + lane) * 8;
        #pragma unroll
        for (int ks = 0; ks < 8; ks++) GLD4(S.w1[ks], b1 + ks * 512);
        const __bf16* b2 = wsbf + ELOFF_W2 + (size_t)it * 16384 +
                           ((size_t)(wid * 4) * 64 + lane) * 8;
        #pragma unroll
        for (int ks = 0; ks < 4; ks++) GLD4(S.w2[ks], b2 + ks * 512);
        const __bf16* bp = wsbf + ELOFF_W3P + (size_t)it * 32768 +
                           ((size_t)(wid * 4) * 64 + lane) * 8;
        #pragma unroll
        for (int ks = 0; ks < 4; ks++) GLD4(S.p0[ks], bp + ks * 512);
        const __bf16* bq = bp + 16384;        // (wid+8) half
        #pragma unroll
        for (int ks = 0; ks < 4; ks++) GLD4(S.p1[ks], bq + ks * 512);
        GLD1(S.s0, mb1 + it * 128 + nW);
        GLD1(S.s1, mb2 + it * 128 + nW);
        GLD1(S.s2, embP + nt2 * 256 + n0);
        GLD1(S.s3, embP + nt2 * 256 + n1);
    };

    auto step = [&](int s, const WSet& cur, WSet& nxt) {
        const int i = s & 31, ni = (s + 1) & 31;
        const bool last = s >= 64;

        // issue next set; retire current set (leaves the 24 new in flight)
        issue_set(nxt, s + 1);
        asm volatile("s_waitcnt vmcnt(24)");
        __builtin_amdgcn_sched_barrier(0);

        // per-step LDS-domain scalars
        const float ne2_0 = b2f(ne2S[(q * 32 + i) * 256 + n0]);
        const float ne2_1 = b2f(ne2S[(q * 32 + i) * 256 + n1]);
        bf16x8 anh = *(const bf16x8*)(adjS + ni * 64 + q * 8);
        bf16x8 anl = *(const bf16x8*)(adjS + ni * 64 + 32 + q * 8);
        const float ani = b2f(adjS[ni * 64 + i]) + b2f(adjS[ni * 64 + 32 + i]);

        // ==== B: W1 GEMM on X2 -> Hs1 ====
        {
            f32x4 aa = {0, 0, 0, 0}, ab = {0, 0, 0, 0};
            f32x4 ac = {0, 0, 0, 0}, ad = {0, 0, 0, 0};
            #pragma unroll
            for (int ks = 0; ks < 8; ks += 4) {
                bf16x8 af0 = *(const bf16x8*)(X2 + l3 * XSTR + ks * 32 + q * 8);
                bf16x8 af1 = *(const bf16x8*)(X2 + l3 * XSTR + (ks + 1) * 32 + q * 8);
                bf16x8 af2 = *(const bf16x8*)(X2 + l3 * XSTR + (ks + 2) * 32 + q * 8);
                bf16x8 af3 = *(const bf16x8*)(X2 + l3 * XSTR + (ks + 3) * 32 + q * 8);
                aa = MFMA16(af0, __builtin_bit_cast(bf16x8, cur.w1[ks]), aa);
                ab = MFMA16(af1, __builtin_bit_cast(bf16x8, cur.w1[ks + 1]), ab);
                ac = MFMA16(af2, __builtin_bit_cast(bf16x8, cur.w1[ks + 2]), ac);
                ad = MFMA16(af3, __builtin_bit_cast(bf16x8, cur.w1[ks + 3]), ad);
            }
            float sb = (pickq(aa, q) + pickq(ab, q)) +
                       (pickq(ac, q) + pickq(ad, q)) + cur.s0;
            Hs1[q * HSTR + nW] = f2b(gelu_e(sb));
        }
        bar_lds();

        // ==== C: W2 GEMM; pcP GEMM (inline-reduced); snap old; h2 store ====
        float pc0 = 0.f, pc1 = 0.f, oP0, oP1;
        {
            f32x4 ca = {0, 0, 0, 0}, cb = {0, 0, 0, 0};
            #pragma unroll
            for (int ks = 0; ks < 4; ks += 2) {
                bf16x8 af0 = *(const bf16x8*)(Hs1 + l3 * HSTR + ks * 32 + q * 8);
                bf16x8 af1 = *(const bf16x8*)(Hs1 + l3 * HSTR + (ks + 1) * 32 + q * 8);
                ca = MFMA16(af0, __builtin_bit_cast(bf16x8, cur.w2[ks]), ca);
                cb = MFMA16(af1, __builtin_bit_cast(bf16x8, cur.w2[ks + 1]), cb);
            }
            // pcP: K=32 tile per b=t; all C rows identical (A rows = an);
            // lane keeps only its own tile's element [0].
            #pragma unroll
            for (int t = 0; t < 4; t++) {
                bf16x8 vf0 = *(const bf16x8*)(valsP + (t * 256 + n0) * VSTR + q * 8);
                bf16x8 vf1 = *(const bf16x8*)(valsP + (t * 256 + n1) * VSTR + q * 8);
                f32x4 z = {0, 0, 0, 0};
                f32x4 p0 = MFMA16(anl, vf0, MFMA16(anh, vf0, z));
                f32x4 p1 = MFMA16(anl, vf1, MFMA16(anh, vf1, z));
                pc0 = (q == t) ? p0[0] : pc0;
                pc1 = (q == t) ? p1[0] : pc1;
            }
            oP0 = b2f(valsP[(q * 256 + n0) * VSTR + i]);
            oP1 = b2f(valsP[(q * 256 + n1) * VSTR + i]);
            float scv = pickq(ca, q) + pickq(cb, q) + cur.s1;
            unsigned short hv = f2b(gelu_e(scv));
            Hs2[q * HSTR + nW] = hv;
            if (last)
                h2buf[((size_t)i * 512 + blk * BTILE + q) * 128 + nW] = hv;
        }
        bar_lds();

        // ==== D: W3P GEMM -> valsP[i]; lane-local fixup + gelu -> X2 ====
        {
            f32x4 c0a = {0, 0, 0, 0}, c0b = {0, 0, 0, 0};
            f32x4 c1a = {0, 0, 0, 0}, c1b = {0, 0, 0, 0};
            #pragma unroll
            for (int ks = 0; ks < 4; ks += 2) {
                bf16x8 af0 = *(const bf16x8*)(Hs2 + l3 * HSTR + ks * 32 + q * 8);
                bf16x8 af1 = *(const bf16x8*)(Hs2 + l3 * HSTR + (ks + 1) * 32 + q * 8);
                c0a = MFMA16(af0, __builtin_bit_cast(bf16x8, cur.p0[ks]), c0a);
                c1a = MFMA16(af0, __builtin_bit_cast(bf16x8, cur.p1[ks]), c1a);
                c0b = MFMA16(af1, __builtin_bit_cast(bf16x8, cur.p0[ks + 1]), c0b);
                c1b = MFMA16(af1, __builtin_bit_cast(bf16x8, cur.p1[ks + 1]), c1b);
            }
            float nP0 = pickq(c0a, q) + pickq(c0b, q) + ne2_0;   // ne2S incl b3P
            float nP1 = pickq(c1a, q) + pickq(c1b, q) + ne2_1;
            unsigned short ur0 = f2b(nP0), ur1 = f2b(nP1);
            valsP[(q * 256 + n0) * VSTR + i] = ur0;
            valsP[(q * 256 + n1) * VSTR + i] = ur1;
            float x0 = pc0 + ani * (b2f(ur0) - oP0) + cur.s2;
            float x1 = pc1 + ani * (b2f(ur1) - oP1) + cur.s3;
            X2[q * XSTR + n0] = f2b(gelu_e(x0));
            X2[q * XSTR + n1] = f2b(gelu_e(x1));
        }
        bar_lds();
    };

    WSet A, B;
    issue_set(A, 0);
    asm volatile("s_waitcnt vmcnt(0)");
    __builtin_amdgcn_sched_barrier(0);
    for (int ss = 0; ss < 48; ss++) {
        step(2 * ss,     A, B);
        step(2 * ss + 1, B, A);
    }
}

// ---------------------------------------------------------------------------
// post_out (256 blocks x 256): outp = h2 @ W3 + b3 + ne  (ne already in outp).
// Wave gid in [0,1024): i = gid>>5, bt = gid&31 -> rows b = bt*16..+15.
// ---------------------------------------------------------------------------
__global__ __launch_bounds__(256) void
post_out(const unsigned short* __restrict__ h2buf, const __bf16* __restrict__ wsbf,
         const float* __restrict__ mb3, float* __restrict__ outp) {
    const int tid = threadIdx.x;
    const int wid = tid >> 6, lane = tid & 63, l15 = lane & 15, q = lane >> 4;
    const int gid = blockIdx.x * 4 + wid;
    const int i = gid >> 5, bt = gid & 31;
    bf16x8 af[4];
    #pragma unroll
    for (int ks = 0; ks < 4; ks++)
        af[ks] = *(const bf16x8*)(h2buf + ((size_t)i * 512 + bt * 16 + l15) * 128 +
                                  ks * 32 + q * 8);
    #pragma unroll 4
    for (int nt = 0; nt < 16; nt++) {
        f32x4 e4 = {0, 0, 0, 0}, o4 = {0, 0, 0, 0};
        #pragma unroll
        for (int ks = 0; ks < 4; ks += 2) {
            bf16x8 b0 = *(const bf16x8*)(wsbf + ELOFF_W3 + (size_t)i * 32768 +
                                         ((nt * 4 + ks) * 64 + lane) * 8);
            bf16x8 b1 = *(const bf16x8*)(wsbf + ELOFF_W3 + (size_t)i * 32768 +
                                         ((nt * 4 + ks + 1) * 64 + lane) * 8);
            e4 = MFMA16(af[ks], b0, e4);
            o4 = MFMA16(af[ks + 1], b1, o4);
        }
        f32x4 a = e4 + o4;
        float bv = mb3[i * 256 + nt * 16 + l15];
        #pragma unroll
        for (int rr = 0; rr < 4; rr++) {
            int b = bt * 16 + q * 4 + rr;
            size_t o = ((size_t)b * 32 + i) * 256 + nt * 16 + l15;
            outp[o] = a[rr] + bv + outp[o];
        }
    }
}

extern "C" void kernel_launch(void* const* d_in, const int* in_sizes, int n_in,
                              void* d_out, int out_size, void* d_ws, size_t ws_size,
                              hipStream_t stream) {
    (void)in_sizes; (void)n_in; (void)out_size; (void)ws_size;
    const float* noise = (const float*)d_in[0];
    const float* edge  = (const float*)d_in[1];
    const float* emb   = (const float*)d_in[2];
    const float* paW   = (const float*)d_in[3];
    const float* pab   = (const float*)d_in[4];
    const float* mW1   = (const float*)d_in[5];
    const float* mb1   = (const float*)d_in[6];
    const float* mW2   = (const float*)d_in[7];
    const float* mb2   = (const float*)d_in[8];
    const float* mW3   = (const float*)d_in[9];
    const float* mb3   = (const float*)d_in[10];
    const float* neW   = (const float*)d_in[11];
    const float* neb   = (const float*)d_in[12];
    float* outp = (float*)d_out;

    unsigned short* adjb = (unsigned short*)((char*)d_ws + WS_ADJB);
    float* b3P  = (float*)((char*)d_ws + WS_B3P);
    float* embP = (float*)((char*)d_ws + WS_EMBP);
    unsigned short* wsb  = (unsigned short*)((char*)d_ws + WS_WSB);
    unsigned short* h2b  = (unsigned short*)((char*)d_ws + WS_H2B);

    prep_all<<<2121, 256, 0, stream>>>(paW, mW1, mW2, mW3, edge, wsb, adjb,
                                       noise, neW, neb, outp, mb3, emb, pab,
                                       b3P, embP);
    scm_main<<<NBLK, 512, 0, stream>>>(embP, b3P, mb1, mb2, adjb,
                                       (const __bf16*)wsb, outp, h2b);
    post_out<<<256, 256, 0, stream>>>(h2b, (const __bf16*)wsb, mb3, outp);
}